// Round 3
// baseline (1166.657 us; speedup 1.0000x reference)
//
#include <hip/hip_runtime.h>
#include <hip/hip_bf16.h>
#include <math.h>

typedef __hip_bfloat16 bf16;
#define BF(x) __bfloat162float(x)
static __device__ __forceinline__ bf16 FB(float x) { return __float2bfloat16(x); }

// Problem constants: B=8, H=W=64, C=128, L=4096, NH=4, HD=32, WIN=8, N=64,
// NW=64, M=B*L=32768.

// Runtime input-dtype detection from xt (N(0,1) data). 0 = bf16, 1 = fp32.
__device__ __forceinline__ int get_mode(const void* xt) {
    const unsigned* w = (const unsigned*)xt;
    int zlo = 0, inband = 0;
    #pragma unroll
    for (int i = 0; i < 32; ++i) {
        unsigned lo = w[i] & 0xFFFFu;
        int e = (int)((lo >> 7) & 0xFF);
        zlo += (lo == 0u || lo == 0x8000u);
        inband += (e >= 100 && e <= 140);
    }
    if (zlo >= 29) return 1;           // fp32 holding bf16-rounded values
    return (inband >= 20) ? 0 : 1;     // bf16 : fp32
}

__device__ __forceinline__ float LD(const void* p, size_t i, int mode) {
    return mode ? ((const float*)p)[i] : BF(((const bf16*)p)[i]);
}

// Tiled GEMM: out[M,N] = A[M,K] @ Bw[ofsW + K,N] + bias[ofsB..]. A: ws bf16.
// EPI 0: store bf16.  1: GELU->bf16.  2: relu(v*auxb)->bf16.
// EPI 4: outf(fp32) += v AND outb = bf16(new).
template <int EPI>
__launch_bounds__(256)
__global__ void gemm_k(const bf16* __restrict__ A, const void* __restrict__ Bw,
                       size_t ofsW, const void* __restrict__ bias, size_t ofsB,
                       bf16* __restrict__ outb, float* __restrict__ outf,
                       const bf16* __restrict__ auxb, const void* __restrict__ dtp,
                       int M, int N, int K) {
    const int mode = get_mode(dtp);
    __shared__ float As[64][16];
    __shared__ float Bs[16][64];
    const int tid = threadIdx.x;
    const int tx = tid & 15, ty = tid >> 4;
    const int bm = blockIdx.y * 64, bn = blockIdx.x * 64;
    float acc[4][4] = {};
    for (int k0 = 0; k0 < K; k0 += 16) {
        #pragma unroll
        for (int i = tid; i < 1024; i += 256) {
            int r = i >> 4, c = i & 15;
            As[r][c] = BF(A[(size_t)(bm + r) * K + (k0 + c)]);
        }
        #pragma unroll
        for (int i = tid; i < 1024; i += 256) {
            int kk = i >> 6, n = i & 63;
            Bs[kk][n] = LD(Bw, ofsW + (size_t)(k0 + kk) * N + (bn + n), mode);
        }
        __syncthreads();
        #pragma unroll
        for (int kk = 0; kk < 16; ++kk) {
            float a[4], b[4];
            #pragma unroll
            for (int i = 0; i < 4; ++i) a[i] = As[ty + 16 * i][kk];
            #pragma unroll
            for (int j = 0; j < 4; ++j) b[j] = Bs[kk][tx + 16 * j];
            #pragma unroll
            for (int i = 0; i < 4; ++i)
                #pragma unroll
                for (int j = 0; j < 4; ++j) acc[i][j] += a[i] * b[j];
        }
        __syncthreads();
    }
    #pragma unroll
    for (int i = 0; i < 4; ++i) {
        int r = bm + ty + 16 * i;
        #pragma unroll
        for (int j = 0; j < 4; ++j) {
            int c = bn + tx + 16 * j;
            float v = acc[i][j] + LD(bias, ofsB + c, mode);
            size_t idx = (size_t)r * N + c;
            if (EPI == 0) {
                outb[idx] = FB(v);
            } else if (EPI == 1) {
                outb[idx] = FB(0.5f * v * (1.0f + erff(v * 0.70710678118654752f)));
            } else if (EPI == 2) {
                float t = v * BF(auxb[idx]);
                outb[idx] = FB(t > 0.f ? t : 0.f);
            } else if (EPI == 4) {
                float nv = outf[idx] + v;
                outf[idx] = nv;
                outb[idx] = FB(nv);
            }
        }
    }
}

// g = concat(xt, hx) @ red_w + red_b.  M=32768, N=128, K=256.  fp32 out.
__launch_bounds__(256)
__global__ void gemm_cat(const void* __restrict__ A1, const void* __restrict__ A2,
                         const void* __restrict__ Bw, const void* __restrict__ bias,
                         float* __restrict__ Cout) {
    const int mode = get_mode(A1);
    const int N = 128, K = 256;
    __shared__ float As[64][16];
    __shared__ float Bs[16][64];
    const int tid = threadIdx.x;
    const int tx = tid & 15, ty = tid >> 4;
    const int bm = blockIdx.y * 64, bn = blockIdx.x * 64;
    float acc[4][4] = {};
    for (int k0 = 0; k0 < K; k0 += 16) {
        #pragma unroll
        for (int i = tid; i < 1024; i += 256) {
            int r = i >> 4, c = i & 15;
            int col = k0 + c;
            As[r][c] = (col < 128) ? LD(A1, (size_t)(bm + r) * 128 + col, mode)
                                   : LD(A2, (size_t)(bm + r) * 128 + (col - 128), mode);
        }
        #pragma unroll
        for (int i = tid; i < 1024; i += 256) {
            int kk = i >> 6, n = i & 63;
            Bs[kk][n] = LD(Bw, (size_t)(k0 + kk) * N + (bn + n), mode);
        }
        __syncthreads();
        #pragma unroll
        for (int kk = 0; kk < 16; ++kk) {
            float a[4], b[4];
            #pragma unroll
            for (int i = 0; i < 4; ++i) a[i] = As[ty + 16 * i][kk];
            #pragma unroll
            for (int j = 0; j < 4; ++j) b[j] = Bs[kk][tx + 16 * j];
            #pragma unroll
            for (int i = 0; i < 4; ++i)
                #pragma unroll
                for (int j = 0; j < 4; ++j) acc[i][j] += a[i] * b[j];
        }
        __syncthreads();
    }
    #pragma unroll
    for (int i = 0; i < 4; ++i) {
        int r = bm + ty + 16 * i;
        #pragma unroll
        for (int j = 0; j < 4; ++j) {
            int c = bn + tx + 16 * j;
            Cout[(size_t)r * N + c] = acc[i][j] + LD(bias, c, mode);
        }
    }
}

// Projection GEMM + window-reverse + roll-back + residual add into g (fp32).
__launch_bounds__(256)
__global__ void gemm_proj(const bf16* __restrict__ A, const void* __restrict__ Bw,
                          size_t ofsW, const void* __restrict__ bias, size_t ofsB,
                          float* __restrict__ G, const void* __restrict__ dtp,
                          int shift) {
    const int mode = get_mode(dtp);
    const int N = 128, K = 128;
    __shared__ float As[64][16];
    __shared__ float Bs[16][64];
    const int tid = threadIdx.x;
    const int tx = tid & 15, ty = tid >> 4;
    const int bm = blockIdx.y * 64, bn = blockIdx.x * 64;
    float acc[4][4] = {};
    for (int k0 = 0; k0 < K; k0 += 16) {
        #pragma unroll
        for (int i = tid; i < 1024; i += 256) {
            int r = i >> 4, c = i & 15;
            As[r][c] = BF(A[(size_t)(bm + r) * K + (k0 + c)]);
        }
        #pragma unroll
        for (int i = tid; i < 1024; i += 256) {
            int kk = i >> 6, n = i & 63;
            Bs[kk][n] = LD(Bw, ofsW + (size_t)(k0 + kk) * N + (bn + n), mode);
        }
        __syncthreads();
        #pragma unroll
        for (int kk = 0; kk < 16; ++kk) {
            float a[4], b[4];
            #pragma unroll
            for (int i = 0; i < 4; ++i) a[i] = As[ty + 16 * i][kk];
            #pragma unroll
            for (int j = 0; j < 4; ++j) b[j] = Bs[kk][tx + 16 * j];
            #pragma unroll
            for (int i = 0; i < 4; ++i)
                #pragma unroll
                for (int j = 0; j < 4; ++j) acc[i][j] += a[i] * b[j];
        }
        __syncthreads();
    }
    #pragma unroll
    for (int i = 0; i < 4; ++i) {
        int r = bm + ty + 16 * i;
        int b = r >> 12, rem = r & 4095;
        int wi = rem >> 6, n = rem & 63;
        int hp = ((wi >> 3) << 3) + (n >> 3);
        int wp = ((wi & 7) << 3) + (n & 7);
        int h = (hp + shift) & 63;
        int w = (wp + shift) & 63;
        int dst = (b << 12) + (h << 6) + w;
        #pragma unroll
        for (int j = 0; j < 4; ++j) {
            int c = bn + tx + 16 * j;
            G[(size_t)dst * N + c] += acc[i][j] + LD(bias, ofsB + c, mode);
        }
    }
}

// LayerNorm over C=128 (fp32 in, bf16 out); optional roll + window partition.
__launch_bounds__(128)
__global__ void ln_k(const float* __restrict__ in, const void* __restrict__ gam,
                     const void* __restrict__ bet, size_t ofs, bf16* __restrict__ out,
                     const void* __restrict__ dtp, int windowed, int shift) {
    const int mode = get_mode(dtp);
    const int row = blockIdx.x, c = threadIdx.x;
    float v = in[(size_t)row * 128 + c];
    float s1 = v, s2 = v * v;
    #pragma unroll
    for (int off = 32; off > 0; off >>= 1) {
        s1 += __shfl_down(s1, off);
        s2 += __shfl_down(s2, off);
    }
    __shared__ float w1[2], w2[2];
    if ((c & 63) == 0) { w1[c >> 6] = s1; w2[c >> 6] = s2; }
    __syncthreads();
    float mu = (w1[0] + w1[1]) * (1.f / 128.f);
    float var = (w2[0] + w2[1]) * (1.f / 128.f) - mu * mu;
    float o = (v - mu) * rsqrtf(var + 1e-5f) * LD(gam, ofs + c, mode) + LD(bet, ofs + c, mode);
    int dst = row;
    if (windowed) {
        int b = row >> 12, rem = row & 4095;
        int h = rem >> 6, w = rem & 63;
        h = (h - shift + 64) & 63;
        w = (w - shift + 64) & 63;
        int wi = ((h >> 3) << 3) + (w >> 3);
        int n = ((h & 7) << 3) + (w & 7);
        dst = (b << 12) + (wi << 6) + n;
    }
    out[(size_t)dst * 128 + c] = FB(o);
}

// Windowed attention: one block per (window, head); thread = query token.
__launch_bounds__(64)
__global__ void attn_k(const bf16* __restrict__ qkv, const void* __restrict__ rp,
                       size_t ofsR, bf16* __restrict__ outp,
                       const void* __restrict__ dtp, int shift) {
    const int mode = get_mode(dtp);
    const int wq = blockIdx.x >> 2;
    const int head = blockIdx.x & 3;
    const int t = threadIdx.x;
    __shared__ float ks[64][33];
    __shared__ float vs[64][33];
    const size_t rbase = (size_t)(wq * 64 + t) * 384 + head * 32;
    float q[32];
    #pragma unroll
    for (int d = 0; d < 32; ++d) {
        q[d] = BF(qkv[rbase + d]) * 0.17677669529663687f;  // HD^-0.5
        ks[t][d] = BF(qkv[rbase + 128 + d]);
        vs[t][d] = BF(qkv[rbase + 256 + d]);
    }
    __syncthreads();
    const int wloc = wq & 63;
    const int wh = (wloc >> 3) << 3, wwb = (wloc & 7) << 3;
    int regt = 0;
    if (shift) {
        int hp = wh + (t >> 3), wp = wwb + (t & 7);
        int rh = hp < 56 ? 0 : (hp < 60 ? 1 : 2);
        int rw = wp < 56 ? 0 : (wp < 60 ? 1 : 2);
        regt = rh * 3 + rw;
    }
    const int ti = t >> 3, tj = t & 7;
    float s[64];
    float mx = -1e30f;
    #pragma unroll
    for (int m = 0; m < 64; ++m) {
        float acc = 0.f;
        #pragma unroll
        for (int d = 0; d < 32; ++d) acc += q[d] * ks[m][d];
        int idx = (ti - (m >> 3) + 7) * 15 + (tj - (m & 7) + 7);
        acc += LD(rp, ofsR + idx * 4 + head, mode);
        if (shift) {
            int hp = wh + (m >> 3), wp = wwb + (m & 7);
            int rh = hp < 56 ? 0 : (hp < 60 ? 1 : 2);
            int rw = wp < 56 ? 0 : (wp < 60 ? 1 : 2);
            if (regt != rh * 3 + rw) acc -= 100.f;
        }
        s[m] = acc;
        mx = fmaxf(mx, acc);
    }
    float l = 0.f;
    #pragma unroll
    for (int m = 0; m < 64; ++m) {
        s[m] = expf(s[m] - mx);
        l += s[m];
    }
    const float inv = 1.f / l;
    const size_t obase = (size_t)(wq * 64 + t) * 128 + head * 32;
    #pragma unroll
    for (int d = 0; d < 32; ++d) {
        float acc = 0.f;
        #pragma unroll
        for (int m = 0; m < 64; ++m) acc += s[m] * vs[m][d];
        outp[obase + d] = FB(acc * inv);
    }
}

// Deformable conv1d local branch; bf16 out in (B,C,L) layout (faithful to the
// reference's .reshape(B, L, C) memory reinterpret).
__launch_bounds__(128)
__global__ void deform_k(const void* __restrict__ xt, const void* __restrict__ off_w,
                         const void* __restrict__ off_b, const void* __restrict__ msk_w,
                         const void* __restrict__ msk_b, bf16* __restrict__ outL) {
    const int mode = get_mode(xt);
    const int bl = blockIdx.x;
    const int b = bl >> 12, l = bl & 4095;
    const int c = threadIdx.x;
    float a6[6] = {};
    #pragma unroll
    for (int j = 0; j < 3; ++j) {
        int ls = l + j - 1;
        float xv = (ls >= 0 && ls < 4096) ? LD(xt, ((size_t)(b << 12) + ls) * 128 + c, mode) : 0.f;
        #pragma unroll
        for (int k = 0; k < 3; ++k) {
            a6[k]     += xv * LD(off_w, (k * 128 + c) * 3 + j, mode);
            a6[3 + k] += xv * LD(msk_w, (k * 128 + c) * 3 + j, mode);
        }
    }
    __shared__ float red[128][6];
    #pragma unroll
    for (int k = 0; k < 6; ++k) red[c][k] = a6[k];
    __syncthreads();
    for (int st = 64; st >= 1; st >>= 1) {
        if (c < st) {
            #pragma unroll
            for (int k = 0; k < 6; ++k) red[c][k] += red[c + st][k];
        }
        __syncthreads();
    }
    __shared__ int s_fp[3], s_cp[3];
    __shared__ float s_al[3], s_mk[3];
    if (c < 3) {
        float off = red[0][c] + LD(off_b, c, mode);
        float pos = (float)l + off;
        pos = fminf(fmaxf(pos, 0.f), 4095.f);
        float fpf = floorf(pos);
        int fp = (int)fpf;
        int cp = fp + 1 > 4095 ? 4095 : fp + 1;
        s_fp[c] = fp; s_cp[c] = cp; s_al[c] = pos - fpf;
        float mv = red[0][3 + c] + LD(msk_b, c, mode);
        s_mk[c] = 1.f / (1.f + expf(-mv));
    }
    __syncthreads();
    float o = 0.f;
    #pragma unroll
    for (int k = 0; k < 3; ++k) {
        float xf = LD(xt, ((size_t)(b << 12) + s_fp[k]) * 128 + c, mode);
        float xc = LD(xt, ((size_t)(b << 12) + s_cp[k]) * 128 + c, mode);
        o += (xf * (1.f - s_al[k]) + xc * s_al[k]) * s_mk[k];
    }
    outL[(size_t)b * 524288 + (size_t)c * 4096 + l] = FB(o);
}

// LSTM gating: out = gate*tanh(gate*(cx+cell)); output dtype follows mode.
__launch_bounds__(256)
__global__ void lstm_k(const bf16* __restrict__ fu, const void* __restrict__ cx,
                       void* __restrict__ out, const void* __restrict__ dtp, int n) {
    const int mode = get_mode(dtp);
    int i = blockIdx.x * 256 + threadIdx.x;
    if (i >= n) return;
    float v = BF(fu[i]);
    float gate = 1.f / (1.f + expf(-v));
    float cell = tanhf(v);
    float cy = gate * (LD(cx, i, mode) + cell);
    float hy = gate * tanhf(cy);
    if (mode) ((float*)out)[i] = hy;
    else      ((bf16*)out)[i] = FB(hy);
}

extern "C" void kernel_launch(void* const* d_in, const int* in_sizes, int n_in,
                              void* d_out, int out_size, void* d_ws, size_t ws_size,
                              hipStream_t stream) {
    (void)out_size; (void)ws_size;
    // Default: setup_inputs() dict order. Fallback: alphabetical-by-name,
    // detected via the in_sizes signature (qkvw=98304 moves from 7 to 23).
    int I[28] = {0,1,2,3,4,5,6,7,8,9,10,11,12,13,14,15,16,17,18,19,20,21,22,23,24,25,26,27};
    if (n_in >= 28 && in_sizes[7] != 98304 && in_sizes[23] == 98304 && in_sizes[26] == 1800) {
        // dict-slot -> alphabetical position:
        // xt hx cx red_w red_b n1g n1b qkvw qkvb rp pw pb n2g n2b f1w f1b f2w
        // f2b off_w off_b msk_w msk_b lf_w lf_b gf_w gf_b ff_w ff_b
        int alt[28] = {27, 9, 0, 25, 24, 15, 14, 23, 22, 26, 21, 20, 17, 16,
                       2, 1, 4, 3, 19, 18, 13, 12, 11, 10, 8, 7, 6, 5};
        for (int i = 0; i < 28; ++i) I[i] = alt[i];
    }
    const void* xt    = d_in[I[0]];
    const void* hx    = d_in[I[1]];
    const void* cx    = d_in[I[2]];
    const void* red_w = d_in[I[3]];
    const void* red_b = d_in[I[4]];
    const void* n1g   = d_in[I[5]];
    const void* n1b   = d_in[I[6]];
    const void* qkvw  = d_in[I[7]];
    const void* qkvb  = d_in[I[8]];
    const void* rp    = d_in[I[9]];
    const void* pw    = d_in[I[10]];
    const void* pb    = d_in[I[11]];
    const void* n2g   = d_in[I[12]];
    const void* n2b   = d_in[I[13]];
    const void* f1w   = d_in[I[14]];
    const void* f1b   = d_in[I[15]];
    const void* f2w   = d_in[I[16]];
    const void* f2b   = d_in[I[17]];
    const void* off_w = d_in[I[18]];
    const void* off_b = d_in[I[19]];
    const void* msk_w = d_in[I[20]];
    const void* msk_b = d_in[I[21]];
    const void* lf_w  = d_in[I[22]];
    const void* lf_b  = d_in[I[23]];
    const void* gf_w  = d_in[I[24]];
    const void* gf_b  = d_in[I[25]];
    const void* ff_w  = d_in[I[26]];
    const void* ff_b  = d_in[I[27]];

    char* wsb = (char*)d_ws;                      // 64 MiB used
    float* g   = (float*)wsb;                     // fp32 residual [0,16M)
    bf16*  Abf = (bf16*)(wsb + 16777216);         // 8 MB
    bf16*  Bbf = (bf16*)(wsb + 25165824);         // 33.5 MB
    bf16*  Cbf = (bf16*)(wsb + 58720256);         // 8 MB (ends at 64 MiB)
    bf16*  lfp = Bbf;                             // 8 MB
    bf16*  fu  = (bf16*)(wsb + 33554432);         // 8 MB, inside Bbf

    // 1. g = concat(xt, hx) @ red_w + red_b
    gemm_cat<<<dim3(2, 512), 256, 0, stream>>>(xt, hx, red_w, red_b, g);

    // 2. two swin blocks (per-depth element offsets applied device-side)
    for (int d = 0; d < 2; ++d) {
        int shift = d ? 4 : 0;
        ln_k<<<32768, 128, 0, stream>>>(g, n1g, n1b, (size_t)d * 128, Abf, xt, 1, shift);
        gemm_k<0><<<dim3(6, 512), 256, 0, stream>>>(Abf, qkvw, (size_t)d * 49152,
                                                    qkvb, (size_t)d * 384, Bbf, nullptr,
                                                    nullptr, xt, 32768, 384, 128);
        attn_k<<<2048, 64, 0, stream>>>(Bbf, rp, (size_t)d * 900, Cbf, xt, shift);
        gemm_proj<<<dim3(2, 512), 256, 0, stream>>>(Cbf, pw, (size_t)d * 16384,
                                                    pb, (size_t)d * 128, g, xt, shift);
        ln_k<<<32768, 128, 0, stream>>>(g, n2g, n2b, (size_t)d * 128, Abf, xt, 0, 0);
        gemm_k<1><<<dim3(8, 512), 256, 0, stream>>>(Abf, f1w, (size_t)d * 65536,
                                                    f1b, (size_t)d * 512, Bbf, nullptr,
                                                    nullptr, xt, 32768, 512, 128);
        gemm_k<4><<<dim3(2, 512), 256, 0, stream>>>(Bbf, f2w, (size_t)d * 65536,
                                                    f2b, (size_t)d * 128, Abf, g,
                                                    nullptr, xt, 32768, 128, 512);
    }

    // 3. local branch: deformable conv -> bf16 (B,C,L) in Cbf
    deform_k<<<32768, 128, 0, stream>>>(xt, off_w, off_b, msk_w, msk_b, Cbf);

    // 4. fusion: lfp = local@lf_w+lf_b ; rel = relu(lfp*(g@gf_w+gf_b)) ; fu
    gemm_k<0><<<dim3(2, 512), 256, 0, stream>>>(Cbf, lf_w, 0, lf_b, 0, lfp, nullptr,
                                                nullptr, xt, 32768, 128, 128);
    gemm_k<2><<<dim3(2, 512), 256, 0, stream>>>(Abf, gf_w, 0, gf_b, 0, Cbf, nullptr,
                                                lfp, xt, 32768, 128, 128);
    gemm_k<0><<<dim3(2, 512), 256, 0, stream>>>(Cbf, ff_w, 0, ff_b, 0, fu, nullptr,
                                                nullptr, xt, 32768, 128, 128);
    // 5. LSTM gating -> out (bf16 or fp32 per detected mode)
    lstm_k<<<16384, 256, 0, stream>>>(fu, cx, d_out, xt, 4194304);
}

// Round 4
// 610.748 us; speedup vs baseline: 1.9102x; 1.9102x over previous
//
#include <hip/hip_runtime.h>
#include <hip/hip_bf16.h>
#include <math.h>

typedef __hip_bfloat16 bf16;
typedef unsigned short u16;
#define BF(x) __bfloat162float(x)
static __device__ __forceinline__ bf16 FB(float x) { return __float2bfloat16(x); }

typedef __attribute__((ext_vector_type(4))) float f32x4;
typedef __attribute__((ext_vector_type(8))) __bf16 bf16x8;

// Problem constants: B=8, H=W=64, C=128, L=4096, NH=4, HD=32, WIN=8, N=64,
// NW=64, M=B*L=32768.

// Runtime input-dtype detection from xt (N(0,1) data). 0 = bf16, 1 = fp32.
// (R3 passed => mode=1 fp32 in practice; keep detection as cheap insurance.)
__device__ __forceinline__ int get_mode(const void* xt) {
    const unsigned* w = (const unsigned*)xt;
    int zlo = 0, inband = 0;
    #pragma unroll
    for (int i = 0; i < 32; ++i) {
        unsigned lo = w[i] & 0xFFFFu;
        int e = (int)((lo >> 7) & 0xFF);
        zlo += (lo == 0u || lo == 0x8000u);
        inband += (e >= 100 && e <= 140);
    }
    if (zlo >= 29) return 1;
    return (inband >= 20) ? 0 : 1;
}

__device__ __forceinline__ float LD(const void* p, size_t i, int mode) {
    return mode ? ((const float*)p)[i] : BF(((const bf16*)p)[i]);
}

// async global->LDS, 16 bytes per lane (global_load_lds_dwordx4)
__device__ __forceinline__ void async16(const u16* g, u16* l) {
    __builtin_amdgcn_global_load_lds(
        (const __attribute__((address_space(1))) unsigned int*)g,
        (__attribute__((address_space(3))) unsigned int*)l, 16, 0, 0);
}

// ---------------------------------------------------------------------------
// Prep: transpose weights to [N][K] bf16 + convert biases/rp/LN/deform params.
// ---------------------------------------------------------------------------
struct PrepT { const void* src; int srcOff, K, N, dstOff; };
struct Prep { PrepT d[29]; int start[30]; };

__global__ void prep_k(Prep p, bf16* __restrict__ dst, const void* __restrict__ dtp) {
    const int mode = get_mode(dtp);
    int i = blockIdx.x * 256 + threadIdx.x;
    if (i >= p.start[29]) return;
    int s = 0;
    while (p.start[s + 1] <= i) ++s;
    int e = i - p.start[s];
    float v;
    if (p.d[s].N > 0) {          // transpose: src[K][N] -> dst[N][K]
        int n = e / p.d[s].K, k = e % p.d[s].K;
        v = LD(p.d[s].src, (size_t)p.d[s].srcOff + (size_t)k * p.d[s].N + n, mode);
    } else {                     // straight copy of K elements
        v = LD(p.d[s].src, (size_t)p.d[s].srcOff + e, mode);
    }
    dst[p.d[s].dstOff + e] = FB(v);
}

// Build bf16 concat X[32768][256] = [xt | hx]
__global__ void xcat_k(const void* __restrict__ xt, const void* __restrict__ hx,
                       bf16* __restrict__ X) {
    const int mode = get_mode(xt);
    int i = blockIdx.x * 256 + threadIdx.x;   // 8,388,608 total
    int r = i >> 8, c = i & 255;
    float v = (c < 128) ? LD(xt, (size_t)r * 128 + c, mode)
                        : LD(hx, (size_t)r * 128 + (c - 128), mode);
    X[i] = FB(v);
}

// ---------------------------------------------------------------------------
// MFMA GEMM: out[M,N] = A[M,K] @ Bt[N,K]^T + bias.  128x128 tile, BK=32,
// 4 waves (2x2 of 64x64), v_mfma_f32_16x16x32_bf16, global_load_lds staging.
// EPI 0: bf16 store. 1: GELU->bf16. 2: relu(v*aux)->bf16.
// EPI 3: window-reverse/roll scatter-add into outf (proj). 4: outf+=v & bf16
// copy to outb. 5: fp32 store.
// ---------------------------------------------------------------------------
template <int EPI>
__launch_bounds__(256)
__global__ void gemm_mfma(const u16* __restrict__ A, const u16* __restrict__ Bt,
                          const bf16* __restrict__ bias, bf16* __restrict__ outb,
                          float* __restrict__ outf, const bf16* __restrict__ aux,
                          int M, int N, int K, int shift) {
    __shared__ __align__(16) u16 Als[4096];   // [128][32]
    __shared__ __align__(16) u16 Bls[4096];   // [128][32]
    const int tid = threadIdx.x;
    const int wave = tid >> 6, lane = tid & 63;
    const int q = lane >> 4, lr = lane & 15;
    const int wm = (wave >> 1) << 6, wn = (wave & 1) << 6;
    const int bm = blockIdx.y << 7, bn = blockIdx.x << 7;
    const f32x4 zero = {0.f, 0.f, 0.f, 0.f};
    f32x4 acc[4][4];
    #pragma unroll
    for (int i = 0; i < 4; ++i)
        #pragma unroll
        for (int j = 0; j < 4; ++j) acc[i][j] = zero;

    for (int k0 = 0; k0 < K; k0 += 32) {
        #pragma unroll
        for (int c = tid; c < 512; c += 256) {
            async16(A + (size_t)(bm + (c >> 2)) * K + k0 + ((c & 3) << 3), Als + (c << 3));
            async16(Bt + (size_t)(bn + (c >> 2)) * K + k0 + ((c & 3) << 3), Bls + (c << 3));
        }
        __syncthreads();
        bf16x8 af[4], bfr[4];
        #pragma unroll
        for (int t = 0; t < 4; ++t) {
            af[t]  = *(const bf16x8*)(Als + ((wm + (t << 4) + lr) << 5) + (q << 3));
            bfr[t] = *(const bf16x8*)(Bls + ((wn + (t << 4) + lr) << 5) + (q << 3));
        }
        #pragma unroll
        for (int mt = 0; mt < 4; ++mt)
            #pragma unroll
            for (int nt = 0; nt < 4; ++nt)
                acc[mt][nt] = __builtin_amdgcn_mfma_f32_16x16x32_bf16(
                    af[mt], bfr[nt], acc[mt][nt], 0, 0, 0);
        __syncthreads();
    }

    #pragma unroll
    for (int nt = 0; nt < 4; ++nt) {
        int col = bn + wn + (nt << 4) + lr;
        float bv = BF(bias[col]);
        #pragma unroll
        for (int mt = 0; mt < 4; ++mt) {
            int row0 = bm + wm + (mt << 4) + (q << 2);
            #pragma unroll
            for (int i = 0; i < 4; ++i) {
                int r = row0 + i;
                float v = acc[mt][nt][i] + bv;
                size_t idx = (size_t)r * N + col;
                if (EPI == 0) {
                    outb[idx] = FB(v);
                } else if (EPI == 1) {
                    outb[idx] = FB(0.5f * v * (1.0f + erff(v * 0.70710678118654752f)));
                } else if (EPI == 2) {
                    float t = v * BF(aux[idx]);
                    outb[idx] = FB(t > 0.f ? t : 0.f);
                } else if (EPI == 3) {
                    int b = r >> 12, rem = r & 4095;
                    int wi = rem >> 6, n = rem & 63;
                    int hp = ((wi >> 3) << 3) + (n >> 3);
                    int wp = ((wi & 7) << 3) + (n & 7);
                    int h = (hp + shift) & 63, w = (wp + shift) & 63;
                    outf[((size_t)((b << 12) + (h << 6) + w)) * 128 + col] += v;
                } else if (EPI == 4) {
                    float nv = outf[idx] + v;
                    outf[idx] = nv;
                    outb[idx] = FB(nv);
                } else if (EPI == 5) {
                    outf[idx] = v;
                }
            }
        }
    }
}

// LayerNorm over C=128 (fp32 in, bf16 out); optional roll + window partition.
__launch_bounds__(128)
__global__ void ln_k(const float* __restrict__ in, const bf16* __restrict__ gam,
                     const bf16* __restrict__ bet, bf16* __restrict__ out,
                     int windowed, int shift) {
    const int row = blockIdx.x, c = threadIdx.x;
    float v = in[(size_t)row * 128 + c];
    float s1 = v, s2 = v * v;
    #pragma unroll
    for (int off = 32; off > 0; off >>= 1) {
        s1 += __shfl_down(s1, off);
        s2 += __shfl_down(s2, off);
    }
    __shared__ float w1[2], w2[2];
    if ((c & 63) == 0) { w1[c >> 6] = s1; w2[c >> 6] = s2; }
    __syncthreads();
    float mu = (w1[0] + w1[1]) * (1.f / 128.f);
    float var = (w2[0] + w2[1]) * (1.f / 128.f) - mu * mu;
    float o = (v - mu) * rsqrtf(var + 1e-5f) * BF(gam[c]) + BF(bet[c]);
    int dst = row;
    if (windowed) {
        int b = row >> 12, rem = row & 4095;
        int h = rem >> 6, w = rem & 63;
        h = (h - shift + 64) & 63;
        w = (w - shift + 64) & 63;
        int wi = ((h >> 3) << 3) + (w >> 3);
        int n = ((h & 7) << 3) + (w & 7);
        dst = (b << 12) + (wi << 6) + n;
    }
    out[(size_t)dst * 128 + c] = FB(o);
}

// Windowed attention: one block per (window, head); thread = query token.
__launch_bounds__(64)
__global__ void attn_k(const bf16* __restrict__ qkv, const bf16* __restrict__ rp,
                       bf16* __restrict__ outp, int shift) {
    const int wq = blockIdx.x >> 2;
    const int head = blockIdx.x & 3;
    const int t = threadIdx.x;
    __shared__ float ks[64][33];
    __shared__ float vs[64][33];
    const size_t rbase = (size_t)(wq * 64 + t) * 384 + head * 32;
    float q[32];
    #pragma unroll
    for (int d = 0; d < 32; ++d) {
        q[d] = BF(qkv[rbase + d]) * 0.17677669529663687f;  // HD^-0.5
        ks[t][d] = BF(qkv[rbase + 128 + d]);
        vs[t][d] = BF(qkv[rbase + 256 + d]);
    }
    __syncthreads();
    const int wloc = wq & 63;
    const int wh = (wloc >> 3) << 3, wwb = (wloc & 7) << 3;
    int regt = 0;
    if (shift) {
        int hp = wh + (t >> 3), wp = wwb + (t & 7);
        int rh = hp < 56 ? 0 : (hp < 60 ? 1 : 2);
        int rw = wp < 56 ? 0 : (wp < 60 ? 1 : 2);
        regt = rh * 3 + rw;
    }
    const int ti = t >> 3, tj = t & 7;
    float s[64];
    float mx = -1e30f;
    #pragma unroll
    for (int m = 0; m < 64; ++m) {
        float acc = 0.f;
        #pragma unroll
        for (int d = 0; d < 32; ++d) acc += q[d] * ks[m][d];
        int idx = (ti - (m >> 3) + 7) * 15 + (tj - (m & 7) + 7);
        acc += BF(rp[idx * 4 + head]);
        if (shift) {
            int hp = wh + (m >> 3), wp = wwb + (m & 7);
            int rh = hp < 56 ? 0 : (hp < 60 ? 1 : 2);
            int rw = wp < 56 ? 0 : (wp < 60 ? 1 : 2);
            if (regt != rh * 3 + rw) acc -= 100.f;
        }
        s[m] = acc;
        mx = fmaxf(mx, acc);
    }
    float l = 0.f;
    #pragma unroll
    for (int m = 0; m < 64; ++m) {
        s[m] = expf(s[m] - mx);
        l += s[m];
    }
    const float inv = 1.f / l;
    const size_t obase = (size_t)(wq * 64 + t) * 128 + head * 32;
    #pragma unroll
    for (int d = 0; d < 32; ++d) {
        float acc = 0.f;
        #pragma unroll
        for (int m = 0; m < 64; ++m) acc += s[m] * vs[m][d];
        outp[obase + d] = FB(acc * inv);
    }
}

// Deformable conv1d local branch; bf16 out in (B,C,L) layout (faithful to the
// reference's .reshape(B, L, C) memory reinterpret). Shuffle reductions.
__launch_bounds__(128)
__global__ void deform_k(const void* __restrict__ xt, const bf16* __restrict__ off_w,
                         const bf16* __restrict__ off_b, const bf16* __restrict__ msk_w,
                         const bf16* __restrict__ msk_b, bf16* __restrict__ outL) {
    const int mode = get_mode(xt);
    const int bl = blockIdx.x;
    const int b = bl >> 12, l = bl & 4095;
    const int c = threadIdx.x;
    const int wave = c >> 6;
    float a6[6] = {};
    #pragma unroll
    for (int j = 0; j < 3; ++j) {
        int ls = l + j - 1;
        float xv = (ls >= 0 && ls < 4096) ? LD(xt, ((size_t)(b << 12) + ls) * 128 + c, mode) : 0.f;
        #pragma unroll
        for (int k = 0; k < 3; ++k) {
            a6[k]     += xv * BF(off_w[(k * 128 + c) * 3 + j]);
            a6[3 + k] += xv * BF(msk_w[(k * 128 + c) * 3 + j]);
        }
    }
    #pragma unroll
    for (int off = 32; off > 0; off >>= 1)
        #pragma unroll
        for (int k = 0; k < 6; ++k) a6[k] += __shfl_down(a6[k], off);
    __shared__ float part[2][6];
    if ((c & 63) == 0)
        #pragma unroll
        for (int k = 0; k < 6; ++k) part[wave][k] = a6[k];
    __syncthreads();
    float o = 0.f;
    #pragma unroll
    for (int k = 0; k < 3; ++k) {
        float off = part[0][k] + part[1][k] + BF(off_b[k]);
        float pos = fminf(fmaxf((float)l + off, 0.f), 4095.f);
        float fpf = floorf(pos);
        int fp = (int)fpf;
        int cp = fp + 1 > 4095 ? 4095 : fp + 1;
        float al = pos - fpf;
        float mv = part[0][3 + k] + part[1][3 + k] + BF(msk_b[k]);
        float mk = 1.f / (1.f + expf(-mv));
        float xf = LD(xt, ((size_t)(b << 12) + fp) * 128 + c, mode);
        float xc = LD(xt, ((size_t)(b << 12) + cp) * 128 + c, mode);
        o += (xf * (1.f - al) + xc * al) * mk;
    }
    outL[(size_t)b * 524288 + (size_t)c * 4096 + l] = FB(o);
}

// LSTM gating: out = gate*tanh(gate*(cx+cell)); output dtype follows mode.
__launch_bounds__(256)
__global__ void lstm_k(const bf16* __restrict__ fu, const void* __restrict__ cx,
                       void* __restrict__ out, const void* __restrict__ dtp, int n) {
    const int mode = get_mode(dtp);
    int i = blockIdx.x * 256 + threadIdx.x;
    if (i >= n) return;
    float v = BF(fu[i]);
    float gate = 1.f / (1.f + expf(-v));
    float cell = tanhf(v);
    float cy = gate * (LD(cx, i, mode) + cell);
    float hy = gate * tanhf(cy);
    if (mode) ((float*)out)[i] = hy;
    else      ((bf16*)out)[i] = FB(hy);
}

extern "C" void kernel_launch(void* const* d_in, const int* in_sizes, int n_in,
                              void* d_out, int out_size, void* d_ws, size_t ws_size,
                              hipStream_t stream) {
    (void)out_size; (void)ws_size;
    int I[28] = {0,1,2,3,4,5,6,7,8,9,10,11,12,13,14,15,16,17,18,19,20,21,22,23,24,25,26,27};
    if (n_in >= 28 && in_sizes[7] != 98304 && in_sizes[23] == 98304 && in_sizes[26] == 1800) {
        int alt[28] = {27, 9, 0, 25, 24, 15, 14, 23, 22, 26, 21, 20, 17, 16,
                       2, 1, 4, 3, 19, 18, 13, 12, 11, 10, 8, 7, 6, 5};
        for (int i = 0; i < 28; ++i) I[i] = alt[i];
    }
    const void* xt    = d_in[I[0]];
    const void* hx    = d_in[I[1]];
    const void* cx    = d_in[I[2]];

    // Workspace (64 MiB):
    //  g    fp32 [0, 16M)
    //  Abf  bf16 [16M, 24M)          LN-out / bf16(g)
    //  Bbf  bf16 [24M, 56M)          Xcat / qkv / mlp-hidden / lfp / fu
    //  Cbf  bf16 [48M, 56M)          attn-out / local / rel (dead during MLP)
    //  Wt   bf16 [56M, 64M)          transposed weights + converted params
    char* wsb = (char*)d_ws;
    float* g    = (float*)wsb;
    u16*   Abf  = (u16*)(wsb + 16777216);
    u16*   Bbf  = (u16*)(wsb + 25165824);
    u16*   Cbf  = (u16*)(wsb + 50331648);
    bf16*  wtb  = (bf16*)(wsb + 58720256);
    u16*   wtu  = (u16*)wtb;
    u16*   Xcat = Bbf;
    u16*   lfp  = Bbf;
    u16*   fu   = Bbf;

    // Wt element offsets
    const int O_REDW = 0, O_QKVW = 32768, O_PW = 131072, O_F1W = 163840,
              O_F2W = 294912, O_LFW = 425984, O_GFW = 442368, O_FFW = 458752,
              O_REDB = 475136, O_QKVB = 475264, O_PB = 476032, O_F1B = 476288,
              O_F2B = 477312, O_LFB = 477568, O_GFB = 477696, O_FFB = 477824,
              O_RP = 477952, O_N1G = 479752, O_N1B = 480008, O_N2G = 480264,
              O_N2B = 480520, O_OW = 480776, O_OB = 481928, O_MW = 481931,
              O_MB = 483083;

    Prep p;
    PrepT descs[29] = {
        {d_in[I[3]],  0,     256, 128, O_REDW},
        {d_in[I[7]],  0,     128, 384, O_QKVW},
        {d_in[I[7]],  49152, 128, 384, O_QKVW + 49152},
        {d_in[I[10]], 0,     128, 128, O_PW},
        {d_in[I[10]], 16384, 128, 128, O_PW + 16384},
        {d_in[I[14]], 0,     128, 512, O_F1W},
        {d_in[I[14]], 65536, 128, 512, O_F1W + 65536},
        {d_in[I[16]], 0,     512, 128, O_F2W},
        {d_in[I[16]], 65536, 512, 128, O_F2W + 65536},
        {d_in[I[22]], 0,     128, 128, O_LFW},
        {d_in[I[24]], 0,     128, 128, O_GFW},
        {d_in[I[26]], 0,     128, 128, O_FFW},
        {d_in[I[4]],  0,  128, 0, O_REDB},
        {d_in[I[8]],  0,  768, 0, O_QKVB},
        {d_in[I[11]], 0,  256, 0, O_PB},
        {d_in[I[15]], 0, 1024, 0, O_F1B},
        {d_in[I[17]], 0,  256, 0, O_F2B},
        {d_in[I[23]], 0,  128, 0, O_LFB},
        {d_in[I[25]], 0,  128, 0, O_GFB},
        {d_in[I[27]], 0,  128, 0, O_FFB},
        {d_in[I[9]],  0, 1800, 0, O_RP},
        {d_in[I[5]],  0,  256, 0, O_N1G},
        {d_in[I[6]],  0,  256, 0, O_N1B},
        {d_in[I[12]], 0,  256, 0, O_N2G},
        {d_in[I[13]], 0,  256, 0, O_N2B},
        {d_in[I[18]], 0, 1152, 0, O_OW},
        {d_in[I[19]], 0,    3, 0, O_OB},
        {d_in[I[20]], 0, 1152, 0, O_MW},
        {d_in[I[21]], 0,    3, 0, O_MB},
    };
    int cum = 0;
    for (int i = 0; i < 29; ++i) {
        p.d[i] = descs[i];
        p.start[i] = cum;
        cum += (descs[i].N > 0) ? descs[i].K * descs[i].N : descs[i].K;
    }
    p.start[29] = cum;

    prep_k<<<(cum + 255) / 256, 256, 0, stream>>>(p, wtb, xt);
    xcat_k<<<32768, 256, 0, stream>>>(xt, hx, (bf16*)Xcat);

    // g = Xcat @ red_w + red_b  (fp32)
    gemm_mfma<5><<<dim3(1, 256), 256, 0, stream>>>(Xcat, wtu + O_REDW, wtb + O_REDB,
                                                   nullptr, g, nullptr, 32768, 128, 256, 0);

    for (int d = 0; d < 2; ++d) {
        int shift = d ? 4 : 0;
        ln_k<<<32768, 128, 0, stream>>>(g, wtb + O_N1G + d * 128, wtb + O_N1B + d * 128,
                                        (bf16*)Abf, 1, shift);
        gemm_mfma<0><<<dim3(3, 256), 256, 0, stream>>>(Abf, wtu + O_QKVW + d * 49152,
                                                       wtb + O_QKVB + d * 384, (bf16*)Bbf,
                                                       nullptr, nullptr, 32768, 384, 128, 0);
        attn_k<<<2048, 64, 0, stream>>>((const bf16*)Bbf, wtb + O_RP + d * 900,
                                        (bf16*)Cbf, shift);
        gemm_mfma<3><<<dim3(1, 256), 256, 0, stream>>>(Cbf, wtu + O_PW + d * 16384,
                                                       wtb + O_PB + d * 128, nullptr, g,
                                                       nullptr, 32768, 128, 128, shift);
        ln_k<<<32768, 128, 0, stream>>>(g, wtb + O_N2G + d * 128, wtb + O_N2B + d * 128,
                                        (bf16*)Abf, 0, 0);
        gemm_mfma<1><<<dim3(4, 256), 256, 0, stream>>>(Abf, wtu + O_F1W + d * 65536,
                                                       wtb + O_F1B + d * 512, (bf16*)Bbf,
                                                       nullptr, nullptr, 32768, 512, 128, 0);
        gemm_mfma<4><<<dim3(1, 256), 256, 0, stream>>>(Bbf, wtu + O_F2W + d * 65536,
                                                       wtb + O_F2B + d * 128, (bf16*)Abf, g,
                                                       nullptr, 32768, 128, 512, 0);
    }

    // local branch -> Cbf (B,C,L)
    deform_k<<<32768, 128, 0, stream>>>(xt, wtb + O_OW, wtb + O_OB, wtb + O_MW,
                                        wtb + O_MB, (bf16*)Cbf);
    // fusion
    gemm_mfma<0><<<dim3(1, 256), 256, 0, stream>>>(Cbf, wtu + O_LFW, wtb + O_LFB,
                                                   (bf16*)lfp, nullptr, nullptr,
                                                   32768, 128, 128, 0);
    gemm_mfma<2><<<dim3(1, 256), 256, 0, stream>>>(Abf, wtu + O_GFW, wtb + O_GFB,
                                                   (bf16*)Cbf, nullptr, (const bf16*)lfp,
                                                   32768, 128, 128, 0);
    gemm_mfma<0><<<dim3(1, 256), 256, 0, stream>>>(Cbf, wtu + O_FFW, wtb + O_FFB,
                                                   (bf16*)fu, nullptr, nullptr,
                                                   32768, 128, 128, 0);
    // LSTM gating -> out
    lstm_k<<<16384, 256, 0, stream>>>((const bf16*)fu, cx, d_out, xt, 4194304);
}

// Round 5
// 553.542 us; speedup vs baseline: 2.1076x; 1.1033x over previous
//
#include <hip/hip_runtime.h>
#include <hip/hip_bf16.h>
#include <math.h>

typedef __hip_bfloat16 bf16;
typedef unsigned short u16;
#define BF(x) __bfloat162float(x)
static __device__ __forceinline__ bf16 FB(float x) { return __float2bfloat16(x); }
static __device__ __forceinline__ u16 FBu(float x) {
    bf16 b = __float2bfloat16(x);
    return *(u16*)&b;
}

typedef __attribute__((ext_vector_type(4))) float f32x4;
typedef __attribute__((ext_vector_type(8))) __bf16 bf16x8;

// Problem: B=8, H=W=64, C=128, L=4096, NH=4, HD=32, WIN=8, N=64, NW=64, M=32768.

// Wt (prepped bf16 weights) element offsets
#define O_REDW 0
#define O_QKVW 32768
#define O_PW   131072
#define O_F1W  163840
#define O_F2W  294912
#define O_LFW  425984
#define O_GFW  442368
#define O_FFW  458752
#define O_REDB 475136
#define O_QKVB 475264
#define O_PB   476032
#define O_F1B  476288
#define O_F2B  477312
#define O_LFB  477568
#define O_GFB  477696
#define O_FFB  477824
#define O_RP   477952
#define O_N1G  479752
#define O_N1B  480008
#define O_N2G  480264
#define O_N2B  480520
#define O_OW   480776
#define O_OB   481928
#define O_MW   481931
#define O_MB   483083

// Runtime input-dtype detection from xt (N(0,1) data). 0 = bf16, 1 = fp32.
__device__ __forceinline__ int get_mode(const void* xt) {
    const unsigned* w = (const unsigned*)xt;
    int zlo = 0, inband = 0;
    #pragma unroll
    for (int i = 0; i < 32; ++i) {
        unsigned lo = w[i] & 0xFFFFu;
        int e = (int)((lo >> 7) & 0xFF);
        zlo += (lo == 0u || lo == 0x8000u);
        inband += (e >= 100 && e <= 140);
    }
    if (zlo >= 29) return 1;
    return (inband >= 20) ? 0 : 1;
}

__device__ __forceinline__ float LD(const void* p, size_t i, int mode) {
    return mode ? ((const float*)p)[i] : BF(((const bf16*)p)[i]);
}

// async global->LDS, 16 bytes per lane
__device__ __forceinline__ void async16(const u16* g, u16* l) {
    __builtin_amdgcn_global_load_lds(
        (const __attribute__((address_space(1))) unsigned int*)g,
        (__attribute__((address_space(3))) unsigned int*)l, 16, 0, 0);
}

// ---------------------------------------------------------------------------
// Prep: transpose weights to [N][K] bf16 + convert params.
// ---------------------------------------------------------------------------
struct PrepT { const void* src; int srcOff, K, N, dstOff; };
struct Prep { PrepT d[29]; int start[30]; };

__global__ void prep_k(Prep p, bf16* __restrict__ dst, const void* __restrict__ dtp) {
    const int mode = get_mode(dtp);
    int i = blockIdx.x * 256 + threadIdx.x;
    if (i >= p.start[29]) return;
    int s = 0;
    while (p.start[s + 1] <= i) ++s;
    int e = i - p.start[s];
    float v;
    if (p.d[s].N > 0) {
        int n = e / p.d[s].K, k = e % p.d[s].K;
        v = LD(p.d[s].src, (size_t)p.d[s].srcOff + (size_t)k * p.d[s].N + n, mode);
    } else {
        v = LD(p.d[s].src, (size_t)p.d[s].srcOff + e, mode);
    }
    dst[p.d[s].dstOff + e] = FB(v);
}

__global__ void xcat_k(const void* __restrict__ xt, const void* __restrict__ hx,
                       bf16* __restrict__ X) {
    const int mode = get_mode(xt);
    int i = blockIdx.x * 256 + threadIdx.x;
    int r = i >> 8, c = i & 255;
    float v = (c < 128) ? LD(xt, (size_t)r * 128 + c, mode)
                        : LD(hx, (size_t)r * 128 + (c - 128), mode);
    X[i] = FB(v);
}

// ---------------------------------------------------------------------------
// MFMA GEMM 128x128 tile, BK=32. EPI 0: bf16 store. 3: window-reverse/roll
// scatter-add into outf. 5: fp32 store.
// ---------------------------------------------------------------------------
template <int EPI>
__launch_bounds__(256)
__global__ void gemm_mfma(const u16* __restrict__ A, const u16* __restrict__ Bt,
                          const bf16* __restrict__ bias, bf16* __restrict__ outb,
                          float* __restrict__ outf, int M, int N, int K, int shift) {
    __shared__ __align__(16) u16 Als[4096];
    __shared__ __align__(16) u16 Bls[4096];
    const int tid = threadIdx.x;
    const int wave = tid >> 6, lane = tid & 63;
    const int q = lane >> 4, lr = lane & 15;
    const int wm = (wave >> 1) << 6, wn = (wave & 1) << 6;
    const int bm = blockIdx.y << 7, bn = blockIdx.x << 7;
    const f32x4 zero = {0.f, 0.f, 0.f, 0.f};
    f32x4 acc[4][4];
    #pragma unroll
    for (int i = 0; i < 4; ++i)
        #pragma unroll
        for (int j = 0; j < 4; ++j) acc[i][j] = zero;

    for (int k0 = 0; k0 < K; k0 += 32) {
        #pragma unroll
        for (int c = tid; c < 512; c += 256) {
            async16(A + (size_t)(bm + (c >> 2)) * K + k0 + ((c & 3) << 3), Als + (c << 3));
            async16(Bt + (size_t)(bn + (c >> 2)) * K + k0 + ((c & 3) << 3), Bls + (c << 3));
        }
        __syncthreads();
        bf16x8 af[4], bfr[4];
        #pragma unroll
        for (int t = 0; t < 4; ++t) {
            af[t]  = *(const bf16x8*)(Als + ((wm + (t << 4) + lr) << 5) + (q << 3));
            bfr[t] = *(const bf16x8*)(Bls + ((wn + (t << 4) + lr) << 5) + (q << 3));
        }
        #pragma unroll
        for (int mt = 0; mt < 4; ++mt)
            #pragma unroll
            for (int nt = 0; nt < 4; ++nt)
                acc[mt][nt] = __builtin_amdgcn_mfma_f32_16x16x32_bf16(
                    af[mt], bfr[nt], acc[mt][nt], 0, 0, 0);
        __syncthreads();
    }

    #pragma unroll
    for (int nt = 0; nt < 4; ++nt) {
        int col = bn + wn + (nt << 4) + lr;
        float bv = BF(bias[col]);
        #pragma unroll
        for (int mt = 0; mt < 4; ++mt) {
            int row0 = bm + wm + (mt << 4) + (q << 2);
            #pragma unroll
            for (int i = 0; i < 4; ++i) {
                int r = row0 + i;
                float v = acc[mt][nt][i] + bv;
                size_t idx = (size_t)r * N + col;
                if (EPI == 0) {
                    outb[idx] = FB(v);
                } else if (EPI == 3) {
                    int b = r >> 12, rem = r & 4095;
                    int wi = rem >> 6, n = rem & 63;
                    int hp = ((wi >> 3) << 3) + (n >> 3);
                    int wp = ((wi & 7) << 3) + (n & 7);
                    int h = (hp + shift) & 63, w = (wp + shift) & 63;
                    outf[((size_t)((b << 12) + (h << 6) + w)) * 128 + col] += v;
                } else if (EPI == 5) {
                    outf[idx] = v;
                }
            }
        }
    }
}

// LayerNorm over C=128 (fp32 in, bf16 out) + roll + window partition.
__launch_bounds__(128)
__global__ void ln_k(const float* __restrict__ in, const bf16* __restrict__ gam,
                     const bf16* __restrict__ bet, bf16* __restrict__ out, int shift) {
    const int row = blockIdx.x, c = threadIdx.x;
    float v = in[(size_t)row * 128 + c];
    float s1 = v, s2 = v * v;
    #pragma unroll
    for (int off = 32; off > 0; off >>= 1) {
        s1 += __shfl_down(s1, off);
        s2 += __shfl_down(s2, off);
    }
    __shared__ float w1[2], w2[2];
    if ((c & 63) == 0) { w1[c >> 6] = s1; w2[c >> 6] = s2; }
    __syncthreads();
    float mu = (w1[0] + w1[1]) * (1.f / 128.f);
    float var = (w2[0] + w2[1]) * (1.f / 128.f) - mu * mu;
    float o = (v - mu) * rsqrtf(var + 1e-5f) * BF(gam[c]) + BF(bet[c]);
    int b = row >> 12, rem = row & 4095;
    int h = rem >> 6, w = rem & 63;
    h = (h - shift + 64) & 63;
    w = (w - shift + 64) & 63;
    int wi = ((h >> 3) << 3) + (w >> 3);
    int n = ((h & 7) << 3) + (w & 7);
    int dst = (b << 12) + (wi << 6) + n;
    out[(size_t)dst * 128 + c] = FB(o);
}

// Windowed attention: one block per (window, head); thread = query token.
__launch_bounds__(64)
__global__ void attn_k(const bf16* __restrict__ qkv, const bf16* __restrict__ rp,
                       bf16* __restrict__ outp, int shift) {
    const int wq = blockIdx.x >> 2;
    const int head = blockIdx.x & 3;
    const int t = threadIdx.x;
    __shared__ float ks[64][33];
    __shared__ float vs[64][33];
    const size_t rbase = (size_t)(wq * 64 + t) * 384 + head * 32;
    float q[32];
    #pragma unroll
    for (int d = 0; d < 32; ++d) {
        q[d] = BF(qkv[rbase + d]) * 0.17677669529663687f;
        ks[t][d] = BF(qkv[rbase + 128 + d]);
        vs[t][d] = BF(qkv[rbase + 256 + d]);
    }
    __syncthreads();
    const int wloc = wq & 63;
    const int wh = (wloc >> 3) << 3, wwb = (wloc & 7) << 3;
    int regt = 0;
    if (shift) {
        int hp = wh + (t >> 3), wp = wwb + (t & 7);
        int rh = hp < 56 ? 0 : (hp < 60 ? 1 : 2);
        int rw = wp < 56 ? 0 : (wp < 60 ? 1 : 2);
        regt = rh * 3 + rw;
    }
    const int ti = t >> 3, tj = t & 7;
    float s[64];
    float mx = -1e30f;
    #pragma unroll
    for (int m = 0; m < 64; ++m) {
        float acc = 0.f;
        #pragma unroll
        for (int d = 0; d < 32; ++d) acc += q[d] * ks[m][d];
        int idx = (ti - (m >> 3) + 7) * 15 + (tj - (m & 7) + 7);
        acc += BF(rp[idx * 4 + head]);
        if (shift) {
            int hp = wh + (m >> 3), wp = wwb + (m & 7);
            int rh = hp < 56 ? 0 : (hp < 60 ? 1 : 2);
            int rw = wp < 56 ? 0 : (wp < 60 ? 1 : 2);
            if (regt != rh * 3 + rw) acc -= 100.f;
        }
        s[m] = acc;
        mx = fmaxf(mx, acc);
    }
    float l = 0.f;
    #pragma unroll
    for (int m = 0; m < 64; ++m) {
        s[m] = expf(s[m] - mx);
        l += s[m];
    }
    const float inv = 1.f / l;
    const size_t obase = (size_t)(wq * 64 + t) * 128 + head * 32;
    #pragma unroll
    for (int d = 0; d < 32; ++d) {
        float acc = 0.f;
        #pragma unroll
        for (int m = 0; m < 64; ++m) acc += s[m] * vs[m][d];
        outp[obase + d] = FB(acc * inv);
    }
}

// ---------------------------------------------------------------------------
// Fused MLP: LN2 + f1 + GELU + f2 + residual into g (+ bf16 copy to gbf).
// One block = 128 rows. 64 KB LDS: Ach(32K) | buf1(16K) | buf2(16K).
// ---------------------------------------------------------------------------
__launch_bounds__(256)
__global__ void mlp_k(float* __restrict__ g, bf16* __restrict__ gbf,
                      const u16* __restrict__ wtu, const bf16* __restrict__ wtb,
                      int d) {
    __shared__ __align__(16) u16 sm[32768];
    u16* Ach  = sm;            // 4 chunks [128][32]
    u16* buf1 = sm + 16384;    // B1 (4x[64][32]) / B2 (2x[128][32])
    u16* buf2 = sm + 24576;    // hidden (2x[128][32])
    const int tid = threadIdx.x;
    const int wave = tid >> 6, lane = tid & 63;
    const int q = lane >> 4, lr = lane & 15;
    const int wm = (wave >> 1) << 6;
    const int wn0 = (wave & 1) << 5;   // stage1: 32-col split
    const int wn = (wave & 1) << 6;    // stage2: 64-col split
    const int bm = blockIdx.x << 7;

    // LN2 over the 128-row tile: thread = (row, half of 64 cols)
    {
        int row = tid >> 1, half = tid & 1;
        const float* gr = g + (size_t)(bm + row) * 128 + half * 64;
        float vals[64];
        float s1 = 0.f, s2 = 0.f;
        #pragma unroll
        for (int i = 0; i < 16; ++i) {
            float4 v4 = *(const float4*)(gr + i * 4);
            vals[i * 4] = v4.x; vals[i * 4 + 1] = v4.y;
            vals[i * 4 + 2] = v4.z; vals[i * 4 + 3] = v4.w;
            s1 += v4.x + v4.y + v4.z + v4.w;
            s2 += v4.x * v4.x + v4.y * v4.y + v4.z * v4.z + v4.w * v4.w;
        }
        s1 += __shfl_xor(s1, 1);
        s2 += __shfl_xor(s2, 1);
        float mu = s1 * (1.f / 128.f);
        float var = s2 * (1.f / 128.f) - mu * mu;
        float inv = rsqrtf(var + 1e-5f);
        #pragma unroll
        for (int i = 0; i < 64; ++i) {
            int c = half * 64 + i;
            float o = (vals[i] - mu) * inv * BF(wtb[O_N2G + d * 128 + c])
                      + BF(wtb[O_N2B + d * 128 + c]);
            Ach[((c >> 5) << 12) + (row << 5) + (c & 31)] = FBu(o);
        }
    }
    __syncthreads();

    const f32x4 zero = {0.f, 0.f, 0.f, 0.f};
    f32x4 acc2[4][4];
    #pragma unroll
    for (int i = 0; i < 4; ++i)
        #pragma unroll
        for (int j = 0; j < 4; ++j) acc2[i][j] = zero;

    for (int h = 0; h < 8; ++h) {
        // stage B1 chunk: 64 hcols x 128 K  (f1wT rows h*64..)
        const u16* B1g = wtu + O_F1W + d * 65536 + h * 8192;
        #pragma unroll
        for (int i = tid; i < 1024; i += 256) {
            int ld = i & 63, u = i >> 6;
            int kc = u & 3, r0 = (u >> 2) << 4;
            async16(B1g + (r0 + (ld >> 2)) * 128 + (kc << 5) + ((ld & 3) << 3),
                    buf1 + kc * 2048 + (r0 << 5) + (ld << 3));
        }
        __syncthreads();
        f32x4 acc1[4][2];
        #pragma unroll
        for (int i = 0; i < 4; ++i) { acc1[i][0] = zero; acc1[i][1] = zero; }
        #pragma unroll
        for (int k0 = 0; k0 < 4; ++k0) {
            bf16x8 af[4], bfr[2];
            #pragma unroll
            for (int t = 0; t < 4; ++t)
                af[t] = *(const bf16x8*)(Ach + (k0 << 12) + ((wm + (t << 4) + lr) << 5) + (q << 3));
            #pragma unroll
            for (int t = 0; t < 2; ++t)
                bfr[t] = *(const bf16x8*)(buf1 + (k0 << 11) + ((wn0 + (t << 4) + lr) << 5) + (q << 3));
            #pragma unroll
            for (int mt = 0; mt < 4; ++mt)
                #pragma unroll
                for (int nt = 0; nt < 2; ++nt)
                    acc1[mt][nt] = __builtin_amdgcn_mfma_f32_16x16x32_bf16(
                        af[mt], bfr[nt], acc1[mt][nt], 0, 0, 0);
        }
        // GELU -> hidden chunks in buf2
        #pragma unroll
        for (int nt = 0; nt < 2; ++nt) {
            int c = wn0 + (nt << 4) + lr;
            float hb = BF(wtb[O_F1B + d * 512 + h * 64 + c]);
            #pragma unroll
            for (int mt = 0; mt < 4; ++mt) {
                #pragma unroll
                for (int i = 0; i < 4; ++i) {
                    int r = wm + (mt << 4) + (q << 2) + i;
                    float v = acc1[mt][nt][i] + hb;
                    float ge = 0.5f * v * (1.0f + erff(v * 0.70710678118654752f));
                    buf2[((c >> 5) << 12) + (r << 5) + (c & 31)] = FBu(ge);
                }
            }
        }
        __syncthreads();
        // stage B2 chunk: 128 n-cols x 64 K (f2wT k-slice h*64..)
        const u16* B2g = wtu + O_F2W + d * 65536 + h * 64;
        #pragma unroll
        for (int i = tid; i < 1024; i += 256) {
            int ld = i & 63, u = i >> 6;
            int kc = u & 1, r0 = (u >> 1) << 4;
            async16(B2g + (r0 + (ld >> 2)) * 512 + (kc << 5) + ((ld & 3) << 3),
                    buf1 + kc * 4096 + (r0 << 5) + (ld << 3));
        }
        __syncthreads();
        #pragma unroll
        for (int kc = 0; kc < 2; ++kc) {
            bf16x8 ah[4], b2[4];
            #pragma unroll
            for (int t = 0; t < 4; ++t) {
                ah[t] = *(const bf16x8*)(buf2 + (kc << 12) + ((wm + (t << 4) + lr) << 5) + (q << 3));
                b2[t] = *(const bf16x8*)(buf1 + (kc << 12) + ((wn + (t << 4) + lr) << 5) + (q << 3));
            }
            #pragma unroll
            for (int mt = 0; mt < 4; ++mt)
                #pragma unroll
                for (int nt = 0; nt < 4; ++nt)
                    acc2[mt][nt] = __builtin_amdgcn_mfma_f32_16x16x32_bf16(
                        ah[mt], b2[nt], acc2[mt][nt], 0, 0, 0);
        }
        __syncthreads();
    }
    // epilogue: residual into g + bf16 copy
    #pragma unroll
    for (int nt = 0; nt < 4; ++nt) {
        int col = wn + (nt << 4) + lr;
        float bv = BF(wtb[O_F2B + d * 128 + col]);
        #pragma unroll
        for (int mt = 0; mt < 4; ++mt) {
            #pragma unroll
            for (int i = 0; i < 4; ++i) {
                int r = bm + wm + (mt << 4) + (q << 2) + i;
                size_t idx = (size_t)r * 128 + col;
                float nv = g[idx] + acc2[mt][nt][i] + bv;
                g[idx] = nv;
                gbf[idx] = FB(nv);
            }
        }
    }
}

// ---------------------------------------------------------------------------
// Fused fusion chain: rel = relu((local@lf+lfb)*(gbf@gf+gfb)); fu = rel@ff+ffb;
// LSTM gate with cx -> out.  One block = 128 rows. 64 KB LDS.
// ---------------------------------------------------------------------------
__launch_bounds__(256)
__global__ void fuse3_k(const u16* __restrict__ Aloc, const u16* __restrict__ Ag,
                        const u16* __restrict__ wtu, const bf16* __restrict__ wtb,
                        const void* __restrict__ cx, void* __restrict__ out,
                        const void* __restrict__ dtp) {
    __shared__ __align__(16) u16 sm[32768];
    u16* sA  = sm;          // Aloc chunk / later Bff chunk
    u16* sG  = sm + 4096;
    u16* sLF = sm + 8192;
    u16* sGF = sm + 12288;
    u16* relb = sm + 16384; // 4 chunks [128][32]
    const int mode = get_mode(dtp);
    const int tid = threadIdx.x;
    const int wave = tid >> 6, lane = tid & 63;
    const int q = lane >> 4, lr = lane & 15;
    const int wm = (wave >> 1) << 6, wn = (wave & 1) << 6;
    const int bm = blockIdx.x << 7;
    const f32x4 zero = {0.f, 0.f, 0.f, 0.f};
    f32x4 acc1[4][4], acc2[4][4];
    #pragma unroll
    for (int i = 0; i < 4; ++i)
        #pragma unroll
        for (int j = 0; j < 4; ++j) { acc1[i][j] = zero; acc2[i][j] = zero; }

    #pragma unroll
    for (int k0 = 0; k0 < 4; ++k0) {
        #pragma unroll
        for (int i = tid; i < 512; i += 256) {
            int ld = i & 63, r0 = (i >> 6) << 4;
            int row = r0 + (ld >> 2), sub = (ld & 3) << 3;
            int dstoff = (r0 << 5) + (ld << 3);
            async16(Aloc + (size_t)(bm + row) * 128 + (k0 << 5) + sub, sA + dstoff);
            async16(Ag   + (size_t)(bm + row) * 128 + (k0 << 5) + sub, sG + dstoff);
            async16(wtu + O_LFW + row * 128 + (k0 << 5) + sub, sLF + dstoff);
            async16(wtu + O_GFW + row * 128 + (k0 << 5) + sub, sGF + dstoff);
        }
        __syncthreads();
        bf16x8 al[4], ag[4], blf[4], bgf[4];
        #pragma unroll
        for (int t = 0; t < 4; ++t) {
            int ro = ((wm + (t << 4) + lr) << 5) + (q << 3);
            int co = ((wn + (t << 4) + lr) << 5) + (q << 3);
            al[t]  = *(const bf16x8*)(sA + ro);
            ag[t]  = *(const bf16x8*)(sG + ro);
            blf[t] = *(const bf16x8*)(sLF + co);
            bgf[t] = *(const bf16x8*)(sGF + co);
        }
        #pragma unroll
        for (int mt = 0; mt < 4; ++mt)
            #pragma unroll
            for (int nt = 0; nt < 4; ++nt) {
                acc1[mt][nt] = __builtin_amdgcn_mfma_f32_16x16x32_bf16(
                    al[mt], blf[nt], acc1[mt][nt], 0, 0, 0);
                acc2[mt][nt] = __builtin_amdgcn_mfma_f32_16x16x32_bf16(
                    ag[mt], bgf[nt], acc2[mt][nt], 0, 0, 0);
            }
        __syncthreads();
    }
    // rel -> LDS chunks
    #pragma unroll
    for (int nt = 0; nt < 4; ++nt) {
        int c = wn + (nt << 4) + lr;
        float lfb = BF(wtb[O_LFB + c]);
        float gfb = BF(wtb[O_GFB + c]);
        #pragma unroll
        for (int mt = 0; mt < 4; ++mt) {
            #pragma unroll
            for (int i = 0; i < 4; ++i) {
                int r = wm + (mt << 4) + (q << 2) + i;
                float t1 = acc1[mt][nt][i] + lfb;
                float t2 = acc2[mt][nt][i] + gfb;
                float rel = t1 * t2;
                relb[((c >> 5) << 12) + (r << 5) + (c & 31)] = FBu(rel > 0.f ? rel : 0.f);
            }
        }
    }
    __syncthreads();
    f32x4 acc3[4][4];
    #pragma unroll
    for (int i = 0; i < 4; ++i)
        #pragma unroll
        for (int j = 0; j < 4; ++j) acc3[i][j] = zero;
    #pragma unroll
    for (int k0 = 0; k0 < 4; ++k0) {
        #pragma unroll
        for (int i = tid; i < 512; i += 256) {
            int ld = i & 63, r0 = (i >> 6) << 4;
            int row = r0 + (ld >> 2), sub = (ld & 3) << 3;
            async16(wtu + O_FFW + row * 128 + (k0 << 5) + sub, sA + (r0 << 5) + (ld << 3));
        }
        __syncthreads();
        bf16x8 ar[4], bff[4];
        #pragma unroll
        for (int t = 0; t < 4; ++t) {
            ar[t]  = *(const bf16x8*)(relb + (k0 << 12) + ((wm + (t << 4) + lr) << 5) + (q << 3));
            bff[t] = *(const bf16x8*)(sA + ((wn + (t << 4) + lr) << 5) + (q << 3));
        }
        #pragma unroll
        for (int mt = 0; mt < 4; ++mt)
            #pragma unroll
            for (int nt = 0; nt < 4; ++nt)
                acc3[mt][nt] = __builtin_amdgcn_mfma_f32_16x16x32_bf16(
                    ar[mt], bff[nt], acc3[mt][nt], 0, 0, 0);
        __syncthreads();
    }
    // LSTM epilogue
    #pragma unroll
    for (int nt = 0; nt < 4; ++nt) {
        int col = wn + (nt << 4) + lr;
        float ffb = BF(wtb[O_FFB + col]);
        #pragma unroll
        for (int mt = 0; mt < 4; ++mt) {
            #pragma unroll
            for (int i = 0; i < 4; ++i) {
                int r = bm + wm + (mt << 4) + (q << 2) + i;
                size_t idx = (size_t)r * 128 + col;
                float v = acc3[mt][nt][i] + ffb;
                float gate = 1.f / (1.f + expf(-v));
                float cell = tanhf(v);
                float cy = gate * (LD(cx, idx, mode) + cell);
                float hy = gate * tanhf(cy);
                if (mode) ((float*)out)[idx] = hy;
                else      ((bf16*)out)[idx] = FB(hy);
            }
        }
    }
}

// ---------------------------------------------------------------------------
// Deformable conv1d local branch; bf16 out in (B,C,L) layout, coalesced
// writes via LDS tile. Block = (b, 64 l's). 256 threads.
// ---------------------------------------------------------------------------
__launch_bounds__(256)
__global__ void deform_k(const void* __restrict__ xt, const bf16* __restrict__ wtb,
                         bf16* __restrict__ outL) {
    __shared__ __align__(16) u16 ot[128 * 72];
    __shared__ int s_fp[192], s_cp[192];
    __shared__ float s_al[192], s_mk[192];
    const int mode = get_mode(xt);
    const int tid = threadIdx.x;
    const int wave = tid >> 6, lane = tid & 63;
    const int b = blockIdx.x >> 6;
    const int l0 = (blockIdx.x & 63) << 6;
    // hoist per-lane weights: c1 = lane, c2 = lane + 64
    float wo[3][3][2], wmk[3][3][2];
    #pragma unroll
    for (int k = 0; k < 3; ++k)
        #pragma unroll
        for (int j = 0; j < 3; ++j) {
            wo[k][j][0]  = BF(wtb[O_OW + (k * 128 + lane) * 3 + j]);
            wo[k][j][1]  = BF(wtb[O_OW + (k * 128 + lane + 64) * 3 + j]);
            wmk[k][j][0] = BF(wtb[O_MW + (k * 128 + lane) * 3 + j]);
            wmk[k][j][1] = BF(wtb[O_MW + (k * 128 + lane + 64) * 3 + j]);
        }
    // phase 1: wave w handles l_loc = w*16 .. w*16+15
    for (int il = 0; il < 16; ++il) {
        int l_loc = wave * 16 + il;
        int l = l0 + l_loc;
        float a6[6] = {};
        #pragma unroll
        for (int j = 0; j < 3; ++j) {
            int row = l + j - 1;
            if (row >= 0 && row < 4096) {
                size_t base = ((size_t)(b << 12) + row) * 128;
                float x0 = LD(xt, base + lane, mode);
                float x1 = LD(xt, base + lane + 64, mode);
                #pragma unroll
                for (int k = 0; k < 3; ++k) {
                    a6[k]     += x0 * wo[k][j][0]  + x1 * wo[k][j][1];
                    a6[3 + k] += x0 * wmk[k][j][0] + x1 * wmk[k][j][1];
                }
            }
        }
        #pragma unroll
        for (int off = 32; off > 0; off >>= 1)
            #pragma unroll
            for (int k = 0; k < 6; ++k) a6[k] += __shfl_down(a6[k], off);
        if (lane == 0) {
            #pragma unroll
            for (int k = 0; k < 3; ++k) {
                float off = a6[k] + BF(wtb[O_OB + k]);
                float pos = fminf(fmaxf((float)l + off, 0.f), 4095.f);
                float fpf = floorf(pos);
                int fp = (int)fpf;
                int cp = fp + 1 > 4095 ? 4095 : fp + 1;
                s_fp[l_loc * 3 + k] = fp;
                s_cp[l_loc * 3 + k] = cp;
                s_al[l_loc * 3 + k] = pos - fpf;
                float mv = a6[3 + k] + BF(wtb[O_MB + k]);
                s_mk[l_loc * 3 + k] = 1.f / (1.f + expf(-mv));
            }
        }
    }
    __syncthreads();
    // phase 2: gather, lanes span c (coalesced reads); stage tile in LDS
    {
        int c = tid & 127, lh = tid >> 7;
        for (int it = 0; it < 32; ++it) {
            int l_loc = lh * 32 + it;
            float o = 0.f;
            #pragma unroll
            for (int k = 0; k < 3; ++k) {
                int fp = s_fp[l_loc * 3 + k];
                int cp = s_cp[l_loc * 3 + k];
                float al = s_al[l_loc * 3 + k];
                float mk = s_mk[l_loc * 3 + k];
                float xf = LD(xt, ((size_t)(b << 12) + fp) * 128 + c, mode);
                float xc = LD(xt, ((size_t)(b << 12) + cp) * 128 + c, mode);
                o += (xf * (1.f - al) + xc * al) * mk;
            }
            ot[c * 72 + l_loc] = FBu(o);
        }
    }
    __syncthreads();
    // write phase: full-line coalesced; thread covers 16 u16 (32B segment? no:
    // 8 lanes x 16B = 128B per c-row)
    #pragma unroll
    for (int pass = 0; pass < 4; ++pass) {
        int cc = pass * 32 + (tid >> 3);
        int oo = tid & 7;
        const uint4 v = *(const uint4*)(ot + cc * 72 + oo * 8);
        *(uint4*)(outL + (size_t)b * 524288 + (size_t)cc * 4096 + l0 + oo * 8) = v;
    }
}

extern "C" void kernel_launch(void* const* d_in, const int* in_sizes, int n_in,
                              void* d_out, int out_size, void* d_ws, size_t ws_size,
                              hipStream_t stream) {
    (void)out_size; (void)ws_size;
    int I[28] = {0,1,2,3,4,5,6,7,8,9,10,11,12,13,14,15,16,17,18,19,20,21,22,23,24,25,26,27};
    if (n_in >= 28 && in_sizes[7] != 98304 && in_sizes[23] == 98304 && in_sizes[26] == 1800) {
        int alt[28] = {27, 9, 0, 25, 24, 15, 14, 23, 22, 26, 21, 20, 17, 16,
                       2, 1, 4, 3, 19, 18, 13, 12, 11, 10, 8, 7, 6, 5};
        for (int i = 0; i < 28; ++i) I[i] = alt[i];
    }
    const void* xt = d_in[I[0]];
    const void* hx = d_in[I[1]];
    const void* cx = d_in[I[2]];

    char* wsb = (char*)d_ws;
    float* g    = (float*)wsb;                    // fp32 residual [0,16M)
    u16*   Abf  = (u16*)(wsb + 16777216);         // LN1-out / bf16(g)
    u16*   Bbf  = (u16*)(wsb + 25165824);         // Xcat / qkv
    u16*   Cbf  = (u16*)(wsb + 50331648);         // attn-out / local
    bf16*  wtb  = (bf16*)(wsb + 58720256);
    u16*   wtu  = (u16*)wtb;

    Prep p;
    PrepT descs[29] = {
        {d_in[I[3]],  0,     256, 128, O_REDW},
        {d_in[I[7]],  0,     128, 384, O_QKVW},
        {d_in[I[7]],  49152, 128, 384, O_QKVW + 49152},
        {d_in[I[10]], 0,     128, 128, O_PW},
        {d_in[I[10]], 16384, 128, 128, O_PW + 16384},
        {d_in[I[14]], 0,     128, 512, O_F1W},
        {d_in[I[14]], 65536, 128, 512, O_F1W + 65536},
        {d_in[I[16]], 0,     512, 128, O_F2W},
        {d_in[I[16]], 65536, 512, 128, O_F2W + 65536},
        {d_in[I[22]], 0,     128, 128, O_LFW},
        {d_in[I[24]], 0,     128, 128, O_GFW},
        {d_in[I[26]], 0,     128, 128, O_FFW},
        {d_in[I[4]],  0,  128, 0, O_REDB},
        {d_in[I[8]],  0,  768, 0, O_QKVB},
        {d_in[I[11]], 0,  256, 0, O_PB},
        {d_in[I[15]], 0, 1024, 0, O_F1B},
        {d_in[I[17]], 0,  256, 0, O_F2B},
        {d_in[I[23]], 0,  128, 0, O_LFB},
        {d_in[I[25]], 0,  128, 0, O_GFB},
        {d_in[I[27]], 0,  128, 0, O_FFB},
        {d_in[I[9]],  0, 1800, 0, O_RP},
        {d_in[I[5]],  0,  256, 0, O_N1G},
        {d_in[I[6]],  0,  256, 0, O_N1B},
        {d_in[I[12]], 0,  256, 0, O_N2G},
        {d_in[I[13]], 0,  256, 0, O_N2B},
        {d_in[I[18]], 0, 1152, 0, O_OW},
        {d_in[I[19]], 0,    3, 0, O_OB},
        {d_in[I[20]], 0, 1152, 0, O_MW},
        {d_in[I[21]], 0,    3, 0, O_MB},
    };
    int cum = 0;
    for (int i = 0; i < 29; ++i) {
        p.d[i] = descs[i];
        p.start[i] = cum;
        cum += (descs[i].N > 0) ? descs[i].K * descs[i].N : descs[i].K;
    }
    p.start[29] = cum;

    prep_k<<<(cum + 255) / 256, 256, 0, stream>>>(p, wtb, xt);
    xcat_k<<<32768, 256, 0, stream>>>(xt, hx, (bf16*)Bbf);

    // g = Xcat @ red_w + red_b (fp32)
    gemm_mfma<5><<<dim3(1, 256), 256, 0, stream>>>(Bbf, wtu + O_REDW, wtb + O_REDB,
                                                   nullptr, g, 32768, 128, 256, 0);

    for (int d = 0; d < 2; ++d) {
        int shift = d ? 4 : 0;
        ln_k<<<32768, 128, 0, stream>>>(g, wtb + O_N1G + d * 128, wtb + O_N1B + d * 128,
                                        (bf16*)Abf, shift);
        gemm_mfma<0><<<dim3(3, 256), 256, 0, stream>>>(Abf, wtu + O_QKVW + d * 49152,
                                                       wtb + O_QKVB + d * 384, (bf16*)Bbf,
                                                       nullptr, 32768, 384, 128, 0);
        attn_k<<<2048, 64, 0, stream>>>((const bf16*)Bbf, wtb + O_RP + d * 900,
                                        (bf16*)Cbf, shift);
        gemm_mfma<3><<<dim3(1, 256), 256, 0, stream>>>(Cbf, wtu + O_PW + d * 16384,
                                                       wtb + O_PB + d * 128, nullptr, g,
                                                       32768, 128, 128, shift);
        mlp_k<<<256, 256, 0, stream>>>(g, (bf16*)Abf, wtu, wtb, d);
    }

    // local branch -> Cbf (B,C,L)
    deform_k<<<512, 256, 0, stream>>>(xt, wtb, (bf16*)Cbf);
    // fused fusion chain + LSTM -> out
    fuse3_k<<<256, 256, 0, stream>>>(Cbf, Abf, wtu, wtb, cx, d_out, xt);
}

// Round 6
// 496.997 us; speedup vs baseline: 2.3474x; 1.1138x over previous
//
#include <hip/hip_runtime.h>
#include <hip/hip_bf16.h>
#include <math.h>

typedef __hip_bfloat16 bf16;
typedef unsigned short u16;
#define BF(x) __bfloat162float(x)
static __device__ __forceinline__ bf16 FB(float x) { return __float2bfloat16(x); }
static __device__ __forceinline__ u16 FBu(float x) {
    bf16 b = __float2bfloat16(x);
    return *(u16*)&b;
}

typedef __attribute__((ext_vector_type(4))) float f32x4;
typedef __attribute__((ext_vector_type(8))) __bf16 bf16x8;

// Problem: B=8, H=W=64, C=128, L=4096, NH=4, HD=32, WIN=8, N=64, NW=64, M=32768.

// Wt (prepped bf16 weights) element offsets
#define O_REDW 0
#define O_QKVW 32768
#define O_PW   131072
#define O_F1W  163840
#define O_F2W  294912
#define O_LFW  425984
#define O_GFW  442368
#define O_FFW  458752
#define O_REDB 475136
#define O_QKVB 475264
#define O_PB   476032
#define O_F1B  476288
#define O_F2B  477312
#define O_LFB  477568
#define O_GFB  477696
#define O_FFB  477824
#define O_RP   477952
#define O_N1G  479752
#define O_N1B  480008
#define O_N2G  480264
#define O_N2B  480520
#define O_OW   480776
#define O_OB   481928
#define O_MW   481931
#define O_MB   483083

// Runtime input-dtype detection from xt (N(0,1) data). 0 = bf16, 1 = fp32.
__device__ __forceinline__ int get_mode(const void* xt) {
    const unsigned* w = (const unsigned*)xt;
    int zlo = 0, inband = 0;
    #pragma unroll
    for (int i = 0; i < 32; ++i) {
        unsigned lo = w[i] & 0xFFFFu;
        int e = (int)((lo >> 7) & 0xFF);
        zlo += (lo == 0u || lo == 0x8000u);
        inband += (e >= 100 && e <= 140);
    }
    if (zlo >= 29) return 1;
    return (inband >= 20) ? 0 : 1;
}

__device__ __forceinline__ float LD(const void* p, size_t i, int mode) {
    return mode ? ((const float*)p)[i] : BF(((const bf16*)p)[i]);
}

// async global->LDS, 16 bytes per lane
__device__ __forceinline__ void async16(const u16* g, u16* l) {
    __builtin_amdgcn_global_load_lds(
        (const __attribute__((address_space(1))) unsigned int*)g,
        (__attribute__((address_space(3))) unsigned int*)l, 16, 0, 0);
}

// ---------------------------------------------------------------------------
// Prep: transpose weights to [N][K] bf16 + convert params.
// ---------------------------------------------------------------------------
struct PrepT { const void* src; int srcOff, K, N, dstOff; };
struct Prep { PrepT d[29]; int start[30]; };

__global__ void prep_k(Prep p, bf16* __restrict__ dst, const void* __restrict__ dtp) {
    const int mode = get_mode(dtp);
    int i = blockIdx.x * 256 + threadIdx.x;
    if (i >= p.start[29]) return;
    int s = 0;
    while (p.start[s + 1] <= i) ++s;
    int e = i - p.start[s];
    float v;
    if (p.d[s].N > 0) {
        int n = e / p.d[s].K, k = e % p.d[s].K;
        v = LD(p.d[s].src, (size_t)p.d[s].srcOff + (size_t)k * p.d[s].N + n, mode);
    } else {
        v = LD(p.d[s].src, (size_t)p.d[s].srcOff + e, mode);
    }
    dst[p.d[s].dstOff + e] = FB(v);
}

// Vectorized concat: X[32768][256] = bf16([xt | hx]).  Grid-stride.
__launch_bounds__(256)
__global__ void xcat_k(const void* __restrict__ xt, const void* __restrict__ hx,
                       u16* __restrict__ X) {
    const int mode = get_mode(xt);
    const int total = 32768 * 32;            // groups of 8 elements
    for (int gidx = blockIdx.x * 256 + threadIdx.x; gidx < total;
         gidx += gridDim.x * 256) {
        int r = gidx >> 5, gi = gidx & 31;
        const void* src = (gi < 16) ? xt : hx;
        int c = (gi & 15) << 3;
        u16 outv[8];
        if (mode) {
            const float* s = (const float*)src + (size_t)r * 128 + c;
            float4 a = *(const float4*)s;
            float4 b = *(const float4*)(s + 4);
            outv[0] = FBu(a.x); outv[1] = FBu(a.y); outv[2] = FBu(a.z); outv[3] = FBu(a.w);
            outv[4] = FBu(b.x); outv[5] = FBu(b.y); outv[6] = FBu(b.z); outv[7] = FBu(b.w);
        } else {
            *(uint4*)outv = *(const uint4*)((const u16*)src + (size_t)r * 128 + c);
        }
        *(uint4*)(X + (size_t)r * 256 + (gi << 3)) = *(const uint4*)outv;
    }
}

// ---------------------------------------------------------------------------
// MFMA GEMM 128x128 tile, BK=32. EPI 3: window-reverse/roll scatter-add into
// outf. 5: fp32 store.
// ---------------------------------------------------------------------------
template <int EPI>
__launch_bounds__(256)
__global__ void gemm_mfma(const u16* __restrict__ A, const u16* __restrict__ Bt,
                          const bf16* __restrict__ bias, bf16* __restrict__ outb,
                          float* __restrict__ outf, int M, int N, int K, int shift) {
    __shared__ __align__(16) u16 Als[4096];
    __shared__ __align__(16) u16 Bls[4096];
    const int tid = threadIdx.x;
    const int wave = tid >> 6, lane = tid & 63;
    const int q = lane >> 4, lr = lane & 15;
    const int wm = (wave >> 1) << 6, wn = (wave & 1) << 6;
    const int bm = blockIdx.y << 7, bn = blockIdx.x << 7;
    const f32x4 zero = {0.f, 0.f, 0.f, 0.f};
    f32x4 acc[4][4];
    #pragma unroll
    for (int i = 0; i < 4; ++i)
        #pragma unroll
        for (int j = 0; j < 4; ++j) acc[i][j] = zero;

    for (int k0 = 0; k0 < K; k0 += 32) {
        #pragma unroll
        for (int c = tid; c < 512; c += 256) {
            async16(A + (size_t)(bm + (c >> 2)) * K + k0 + ((c & 3) << 3), Als + (c << 3));
            async16(Bt + (size_t)(bn + (c >> 2)) * K + k0 + ((c & 3) << 3), Bls + (c << 3));
        }
        __syncthreads();
        bf16x8 af[4], bfr[4];
        #pragma unroll
        for (int t = 0; t < 4; ++t) {
            af[t]  = *(const bf16x8*)(Als + ((wm + (t << 4) + lr) << 5) + (q << 3));
            bfr[t] = *(const bf16x8*)(Bls + ((wn + (t << 4) + lr) << 5) + (q << 3));
        }
        #pragma unroll
        for (int mt = 0; mt < 4; ++mt)
            #pragma unroll
            for (int nt = 0; nt < 4; ++nt)
                acc[mt][nt] = __builtin_amdgcn_mfma_f32_16x16x32_bf16(
                    af[mt], bfr[nt], acc[mt][nt], 0, 0, 0);
        __syncthreads();
    }

    #pragma unroll
    for (int nt = 0; nt < 4; ++nt) {
        int col = bn + wn + (nt << 4) + lr;
        float bv = BF(bias[col]);
        #pragma unroll
        for (int mt = 0; mt < 4; ++mt) {
            int row0 = bm + wm + (mt << 4) + (q << 2);
            #pragma unroll
            for (int i = 0; i < 4; ++i) {
                int r = row0 + i;
                float v = acc[mt][nt][i] + bv;
                size_t idx = (size_t)r * N + col;
                if (EPI == 0) {
                    outb[idx] = FB(v);
                } else if (EPI == 3) {
                    int b = r >> 12, rem = r & 4095;
                    int wi = rem >> 6, n = rem & 63;
                    int hp = ((wi >> 3) << 3) + (n >> 3);
                    int wp = ((wi & 7) << 3) + (n & 7);
                    int h = (hp + shift) & 63, w = (wp + shift) & 63;
                    outf[((size_t)((b << 12) + (h << 6) + w)) * 128 + col] += v;
                } else if (EPI == 5) {
                    outf[idx] = v;
                }
            }
        }
    }
}

// ---------------------------------------------------------------------------
// Fused LN1 (+roll+window gather) + QKV GEMM. Block = 128 windowed rows.
// LDS 64KB: Ach 4x[128][32] | Bb 4x[128][32].
// ---------------------------------------------------------------------------
__launch_bounds__(256)
__global__ void qkvln_k(const float* __restrict__ g, const u16* __restrict__ wtu,
                        const bf16* __restrict__ wtb, u16* __restrict__ qkv,
                        int d, int shift) {
    __shared__ __align__(16) u16 sm[32768];
    u16* Ach = sm;
    u16* Bb  = sm + 16384;
    const int tid = threadIdx.x;
    const int wave = tid >> 6, lane = tid & 63;
    const int q = lane >> 4, lr = lane & 15;
    const int wm = (wave >> 1) << 6, wn = (wave & 1) << 6;
    const int bm = blockIdx.x << 7;

    // LN1 with inverse-roll gather from g (windowed row -> source row)
    {
        int row = tid >> 1, half = tid & 1;
        int r = bm + row;
        int b = r >> 12, rem = r & 4095;
        int wi = rem >> 6, n = rem & 63;
        int hp = ((wi >> 3) << 3) + (n >> 3);
        int wp = ((wi & 7) << 3) + (n & 7);
        int h = (hp + shift) & 63, w = (wp + shift) & 63;
        int src = (b << 12) + (h << 6) + w;
        const float* gr = g + (size_t)src * 128 + half * 64;
        float vals[64];
        float s1 = 0.f, s2 = 0.f;
        #pragma unroll
        for (int i = 0; i < 16; ++i) {
            float4 v4 = *(const float4*)(gr + i * 4);
            vals[i * 4] = v4.x; vals[i * 4 + 1] = v4.y;
            vals[i * 4 + 2] = v4.z; vals[i * 4 + 3] = v4.w;
            s1 += v4.x + v4.y + v4.z + v4.w;
            s2 += v4.x * v4.x + v4.y * v4.y + v4.z * v4.z + v4.w * v4.w;
        }
        s1 += __shfl_xor(s1, 1);
        s2 += __shfl_xor(s2, 1);
        float mu = s1 * (1.f / 128.f);
        float var = s2 * (1.f / 128.f) - mu * mu;
        float inv = rsqrtf(var + 1e-5f);
        #pragma unroll
        for (int i = 0; i < 64; ++i) {
            int c = half * 64 + i;
            float o = (vals[i] - mu) * inv * BF(wtb[O_N1G + d * 128 + c])
                      + BF(wtb[O_N1B + d * 128 + c]);
            Ach[((c >> 5) << 12) + (row << 5) + (c & 31)] = FBu(o);
        }
    }
    __syncthreads();

    const f32x4 zero = {0.f, 0.f, 0.f, 0.f};
    for (int nc = 0; nc < 3; ++nc) {
        const u16* Bg = wtu + O_QKVW + d * 49152 + nc * 16384;
        #pragma unroll
        for (int i = tid; i < 2048; i += 256) {
            int kc = i >> 9, c = i & 511;
            async16(Bg + (size_t)(c >> 2) * 128 + (kc << 5) + ((c & 3) << 3),
                    Bb + (kc << 12) + (c << 3));
        }
        __syncthreads();
        f32x4 acc[4][4];
        #pragma unroll
        for (int i = 0; i < 4; ++i)
            #pragma unroll
            for (int j = 0; j < 4; ++j) acc[i][j] = zero;
        #pragma unroll
        for (int k0 = 0; k0 < 4; ++k0) {
            bf16x8 af[4], bfr[4];
            #pragma unroll
            for (int t = 0; t < 4; ++t) {
                af[t]  = *(const bf16x8*)(Ach + (k0 << 12) + ((wm + (t << 4) + lr) << 5) + (q << 3));
                bfr[t] = *(const bf16x8*)(Bb + (k0 << 12) + ((wn + (t << 4) + lr) << 5) + (q << 3));
            }
            #pragma unroll
            for (int mt = 0; mt < 4; ++mt)
                #pragma unroll
                for (int nt = 0; nt < 4; ++nt)
                    acc[mt][nt] = __builtin_amdgcn_mfma_f32_16x16x32_bf16(
                        af[mt], bfr[nt], acc[mt][nt], 0, 0, 0);
        }
        #pragma unroll
        for (int nt = 0; nt < 4; ++nt) {
            int col = wn + (nt << 4) + lr;
            float bv = BF(wtb[O_QKVB + d * 384 + nc * 128 + col]);
            #pragma unroll
            for (int mt = 0; mt < 4; ++mt) {
                #pragma unroll
                for (int i = 0; i < 4; ++i) {
                    int r = bm + wm + (mt << 4) + (q << 2) + i;
                    qkv[(size_t)r * 384 + nc * 128 + col] = FBu(acc[mt][nt][i] + bv);
                }
            }
        }
        __syncthreads();
    }
}

// ---------------------------------------------------------------------------
// Windowed attention: block = one window (4 heads = 4 waves). K/V staged
// transposed [d][m] in fp32 LDS (conflict-free writes, broadcast reads).
// ---------------------------------------------------------------------------
__launch_bounds__(256)
__global__ void attn_k(const u16* __restrict__ qkv, const bf16* __restrict__ rp,
                       u16* __restrict__ outp, int shift) {
    __shared__ float kT[4][32][64];
    __shared__ float vT[4][32][64];
    const int wq = blockIdx.x;
    const int head = threadIdx.x >> 6;
    const int t = threadIdx.x & 63;
    const size_t rbase = (size_t)(wq * 64 + t) * 384 + head * 32;
    float q[32];
    #pragma unroll
    for (int j = 0; j < 4; ++j) {
        bf16x8 qv = *(const bf16x8*)(qkv + rbase + j * 8);
        bf16x8 kv = *(const bf16x8*)(qkv + rbase + 128 + j * 8);
        bf16x8 vv = *(const bf16x8*)(qkv + rbase + 256 + j * 8);
        #pragma unroll
        for (int e = 0; e < 8; ++e) {
            int dd = j * 8 + e;
            q[dd] = (float)qv[e] * 0.17677669529663687f;
            kT[head][dd][t] = (float)kv[e];
            vT[head][dd][t] = (float)vv[e];
        }
    }
    __syncthreads();
    const int wloc = wq & 63;
    const int wh = (wloc >> 3) << 3, wwb = (wloc & 7) << 3;
    int regt = 0;
    if (shift) {
        int hp = wh + (t >> 3), wp = wwb + (t & 7);
        int rh = hp < 56 ? 0 : (hp < 60 ? 1 : 2);
        int rw = wp < 56 ? 0 : (wp < 60 ? 1 : 2);
        regt = rh * 3 + rw;
    }
    const int ti = t >> 3, tj = t & 7;
    float s[64];
    float mx = -1e30f;
    #pragma unroll
    for (int m = 0; m < 64; ++m) {
        float acc = 0.f;
        #pragma unroll
        for (int dd = 0; dd < 32; ++dd) acc += q[dd] * kT[head][dd][m];
        int idx = (ti - (m >> 3) + 7) * 15 + (tj - (m & 7) + 7);
        acc += BF(rp[idx * 4 + head]);
        if (shift) {
            int hp = wh + (m >> 3), wp = wwb + (m & 7);
            int rh = hp < 56 ? 0 : (hp < 60 ? 1 : 2);
            int rw = wp < 56 ? 0 : (wp < 60 ? 1 : 2);
            if (regt != rh * 3 + rw) acc -= 100.f;
        }
        s[m] = acc;
        mx = fmaxf(mx, acc);
    }
    float l = 0.f;
    #pragma unroll
    for (int m = 0; m < 64; ++m) {
        s[m] = expf(s[m] - mx);
        l += s[m];
    }
    const float inv = 1.f / l;
    const size_t obase = (size_t)(wq * 64 + t) * 128 + head * 32;
    #pragma unroll
    for (int j = 0; j < 4; ++j) {
        bf16x8 ov;
        #pragma unroll
        for (int e = 0; e < 8; ++e) {
            int dd = j * 8 + e;
            float a = 0.f;
            #pragma unroll
            for (int m = 0; m < 64; ++m) a += s[m] * vT[head][dd][m];
            ov[e] = (__bf16)(a * inv);
        }
        *(bf16x8*)(outp + obase + j * 8) = ov;
    }
}

// ---------------------------------------------------------------------------
// Fused MLP: LN2 + f1 + GELU + f2 + residual into g (+ bf16 copy to gbf).
// ---------------------------------------------------------------------------
__launch_bounds__(256)
__global__ void mlp_k(float* __restrict__ g, bf16* __restrict__ gbf,
                      const u16* __restrict__ wtu, const bf16* __restrict__ wtb,
                      int d) {
    __shared__ __align__(16) u16 sm[32768];
    u16* Ach  = sm;
    u16* buf1 = sm + 16384;
    u16* buf2 = sm + 24576;
    const int tid = threadIdx.x;
    const int wave = tid >> 6, lane = tid & 63;
    const int q = lane >> 4, lr = lane & 15;
    const int wm = (wave >> 1) << 6;
    const int wn0 = (wave & 1) << 5;
    const int wn = (wave & 1) << 6;
    const int bm = blockIdx.x << 7;

    {
        int row = tid >> 1, half = tid & 1;
        const float* gr = g + (size_t)(bm + row) * 128 + half * 64;
        float vals[64];
        float s1 = 0.f, s2 = 0.f;
        #pragma unroll
        for (int i = 0; i < 16; ++i) {
            float4 v4 = *(const float4*)(gr + i * 4);
            vals[i * 4] = v4.x; vals[i * 4 + 1] = v4.y;
            vals[i * 4 + 2] = v4.z; vals[i * 4 + 3] = v4.w;
            s1 += v4.x + v4.y + v4.z + v4.w;
            s2 += v4.x * v4.x + v4.y * v4.y + v4.z * v4.z + v4.w * v4.w;
        }
        s1 += __shfl_xor(s1, 1);
        s2 += __shfl_xor(s2, 1);
        float mu = s1 * (1.f / 128.f);
        float var = s2 * (1.f / 128.f) - mu * mu;
        float inv = rsqrtf(var + 1e-5f);
        #pragma unroll
        for (int i = 0; i < 64; ++i) {
            int c = half * 64 + i;
            float o = (vals[i] - mu) * inv * BF(wtb[O_N2G + d * 128 + c])
                      + BF(wtb[O_N2B + d * 128 + c]);
            Ach[((c >> 5) << 12) + (row << 5) + (c & 31)] = FBu(o);
        }
    }
    __syncthreads();

    const f32x4 zero = {0.f, 0.f, 0.f, 0.f};
    f32x4 acc2[4][4];
    #pragma unroll
    for (int i = 0; i < 4; ++i)
        #pragma unroll
        for (int j = 0; j < 4; ++j) acc2[i][j] = zero;

    for (int h = 0; h < 8; ++h) {
        const u16* B1g = wtu + O_F1W + d * 65536 + h * 8192;
        #pragma unroll
        for (int i = tid; i < 1024; i += 256) {
            int ld = i & 63, u = i >> 6;
            int kc = u & 3, r0 = (u >> 2) << 4;
            async16(B1g + (r0 + (ld >> 2)) * 128 + (kc << 5) + ((ld & 3) << 3),
                    buf1 + kc * 2048 + (r0 << 5) + (ld << 3));
        }
        __syncthreads();
        f32x4 acc1[4][2];
        #pragma unroll
        for (int i = 0; i < 4; ++i) { acc1[i][0] = zero; acc1[i][1] = zero; }
        #pragma unroll
        for (int k0 = 0; k0 < 4; ++k0) {
            bf16x8 af[4], bfr[2];
            #pragma unroll
            for (int t = 0; t < 4; ++t)
                af[t] = *(const bf16x8*)(Ach + (k0 << 12) + ((wm + (t << 4) + lr) << 5) + (q << 3));
            #pragma unroll
            for (int t = 0; t < 2; ++t)
                bfr[t] = *(const bf16x8*)(buf1 + (k0 << 11) + ((wn0 + (t << 4) + lr) << 5) + (q << 3));
            #pragma unroll
            for (int mt = 0; mt < 4; ++mt)
                #pragma unroll
                for (int nt = 0; nt < 2; ++nt)
                    acc1[mt][nt] = __builtin_amdgcn_mfma_f32_16x16x32_bf16(
                        af[mt], bfr[nt], acc1[mt][nt], 0, 0, 0);
        }
        #pragma unroll
        for (int nt = 0; nt < 2; ++nt) {
            int c = wn0 + (nt << 4) + lr;
            float hb = BF(wtb[O_F1B + d * 512 + h * 64 + c]);
            #pragma unroll
            for (int mt = 0; mt < 4; ++mt) {
                #pragma unroll
                for (int i = 0; i < 4; ++i) {
                    int r = wm + (mt << 4) + (q << 2) + i;
                    float v = acc1[mt][nt][i] + hb;
                    float ge = 0.5f * v * (1.0f + erff(v * 0.70710678118654752f));
                    buf2[((c >> 5) << 12) + (r << 5) + (c & 31)] = FBu(ge);
                }
            }
        }
        __syncthreads();
        const u16* B2g = wtu + O_F2W + d * 65536 + h * 64;
        #pragma unroll
        for (int i = tid; i < 1024; i += 256) {
            int ld = i & 63, u = i >> 6;
            int kc = u & 1, r0 = (u >> 1) << 4;
            async16(B2g + (r0 + (ld >> 2)) * 512 + (kc << 5) + ((ld & 3) << 3),
                    buf1 + kc * 4096 + (r0 << 5) + (ld << 3));
        }
        __syncthreads();
        #pragma unroll
        for (int kc = 0; kc < 2; ++kc) {
            bf16x8 ah[4], b2[4];
            #pragma unroll
            for (int t = 0; t < 4; ++t) {
                ah[t] = *(const bf16x8*)(buf2 + (kc << 12) + ((wm + (t << 4) + lr) << 5) + (q << 3));
                b2[t] = *(const bf16x8*)(buf1 + (kc << 12) + ((wn + (t << 4) + lr) << 5) + (q << 3));
            }
            #pragma unroll
            for (int mt = 0; mt < 4; ++mt)
                #pragma unroll
                for (int nt = 0; nt < 4; ++nt)
                    acc2[mt][nt] = __builtin_amdgcn_mfma_f32_16x16x32_bf16(
                        ah[mt], b2[nt], acc2[mt][nt], 0, 0, 0);
        }
        __syncthreads();
    }
    #pragma unroll
    for (int nt = 0; nt < 4; ++nt) {
        int col = wn + (nt << 4) + lr;
        float bv = BF(wtb[O_F2B + d * 128 + col]);
        #pragma unroll
        for (int mt = 0; mt < 4; ++mt) {
            #pragma unroll
            for (int i = 0; i < 4; ++i) {
                int r = bm + wm + (mt << 4) + (q << 2) + i;
                size_t idx = (size_t)r * 128 + col;
                float nv = g[idx] + acc2[mt][nt][i] + bv;
                g[idx] = nv;
                gbf[idx] = FB(nv);
            }
        }
    }
}

// ---------------------------------------------------------------------------
// Fused fusion chain + LSTM gate -> out.
// ---------------------------------------------------------------------------
__launch_bounds__(256)
__global__ void fuse3_k(const u16* __restrict__ Aloc, const u16* __restrict__ Ag,
                        const u16* __restrict__ wtu, const bf16* __restrict__ wtb,
                        const void* __restrict__ cx, void* __restrict__ out,
                        const void* __restrict__ dtp) {
    __shared__ __align__(16) u16 sm[32768];
    u16* sA  = sm;
    u16* sG  = sm + 4096;
    u16* sLF = sm + 8192;
    u16* sGF = sm + 12288;
    u16* relb = sm + 16384;
    const int mode = get_mode(dtp);
    const int tid = threadIdx.x;
    const int wave = tid >> 6, lane = tid & 63;
    const int q = lane >> 4, lr = lane & 15;
    const int wm = (wave >> 1) << 6, wn = (wave & 1) << 6;
    const int bm = blockIdx.x << 7;
    const f32x4 zero = {0.f, 0.f, 0.f, 0.f};
    f32x4 acc1[4][4], acc2[4][4];
    #pragma unroll
    for (int i = 0; i < 4; ++i)
        #pragma unroll
        for (int j = 0; j < 4; ++j) { acc1[i][j] = zero; acc2[i][j] = zero; }

    #pragma unroll
    for (int k0 = 0; k0 < 4; ++k0) {
        #pragma unroll
        for (int i = tid; i < 512; i += 256) {
            int ld = i & 63, r0 = (i >> 6) << 4;
            int row = r0 + (ld >> 2), sub = (ld & 3) << 3;
            int dstoff = (r0 << 5) + (ld << 3);
            async16(Aloc + (size_t)(bm + row) * 128 + (k0 << 5) + sub, sA + dstoff);
            async16(Ag   + (size_t)(bm + row) * 128 + (k0 << 5) + sub, sG + dstoff);
            async16(wtu + O_LFW + row * 128 + (k0 << 5) + sub, sLF + dstoff);
            async16(wtu + O_GFW + row * 128 + (k0 << 5) + sub, sGF + dstoff);
        }
        __syncthreads();
        bf16x8 al[4], ag[4], blf[4], bgf[4];
        #pragma unroll
        for (int t = 0; t < 4; ++t) {
            int ro = ((wm + (t << 4) + lr) << 5) + (q << 3);
            int co = ((wn + (t << 4) + lr) << 5) + (q << 3);
            al[t]  = *(const bf16x8*)(sA + ro);
            ag[t]  = *(const bf16x8*)(sG + ro);
            blf[t] = *(const bf16x8*)(sLF + co);
            bgf[t] = *(const bf16x8*)(sGF + co);
        }
        #pragma unroll
        for (int mt = 0; mt < 4; ++mt)
            #pragma unroll
            for (int nt = 0; nt < 4; ++nt) {
                acc1[mt][nt] = __builtin_amdgcn_mfma_f32_16x16x32_bf16(
                    al[mt], blf[nt], acc1[mt][nt], 0, 0, 0);
                acc2[mt][nt] = __builtin_amdgcn_mfma_f32_16x16x32_bf16(
                    ag[mt], bgf[nt], acc2[mt][nt], 0, 0, 0);
            }
        __syncthreads();
    }
    #pragma unroll
    for (int nt = 0; nt < 4; ++nt) {
        int c = wn + (nt << 4) + lr;
        float lfb = BF(wtb[O_LFB + c]);
        float gfb = BF(wtb[O_GFB + c]);
        #pragma unroll
        for (int mt = 0; mt < 4; ++mt) {
            #pragma unroll
            for (int i = 0; i < 4; ++i) {
                int r = wm + (mt << 4) + (q << 2) + i;
                float t1 = acc1[mt][nt][i] + lfb;
                float t2 = acc2[mt][nt][i] + gfb;
                float rel = t1 * t2;
                relb[((c >> 5) << 12) + (r << 5) + (c & 31)] = FBu(rel > 0.f ? rel : 0.f);
            }
        }
    }
    __syncthreads();
    f32x4 acc3[4][4];
    #pragma unroll
    for (int i = 0; i < 4; ++i)
        #pragma unroll
        for (int j = 0; j < 4; ++j) acc3[i][j] = zero;
    #pragma unroll
    for (int k0 = 0; k0 < 4; ++k0) {
        #pragma unroll
        for (int i = tid; i < 512; i += 256) {
            int ld = i & 63, r0 = (i >> 6) << 4;
            int row = r0 + (ld >> 2), sub = (ld & 3) << 3;
            async16(wtu + O_FFW + row * 128 + (k0 << 5) + sub, sA + (r0 << 5) + (ld << 3));
        }
        __syncthreads();
        bf16x8 ar[4], bff[4];
        #pragma unroll
        for (int t = 0; t < 4; ++t) {
            ar[t]  = *(const bf16x8*)(relb + (k0 << 12) + ((wm + (t << 4) + lr) << 5) + (q << 3));
            bff[t] = *(const bf16x8*)(sA + ((wn + (t << 4) + lr) << 5) + (q << 3));
        }
        #pragma unroll
        for (int mt = 0; mt < 4; ++mt)
            #pragma unroll
            for (int nt = 0; nt < 4; ++nt)
                acc3[mt][nt] = __builtin_amdgcn_mfma_f32_16x16x32_bf16(
                    ar[mt], bff[nt], acc3[mt][nt], 0, 0, 0);
        __syncthreads();
    }
    #pragma unroll
    for (int nt = 0; nt < 4; ++nt) {
        int col = wn + (nt << 4) + lr;
        float ffb = BF(wtb[O_FFB + col]);
        #pragma unroll
        for (int mt = 0; mt < 4; ++mt) {
            #pragma unroll
            for (int i = 0; i < 4; ++i) {
                int r = bm + wm + (mt << 4) + (q << 2) + i;
                size_t idx = (size_t)r * 128 + col;
                float v = acc3[mt][nt][i] + ffb;
                float gate = 1.f / (1.f + expf(-v));
                float cell = tanhf(v);
                float cy = gate * (LD(cx, idx, mode) + cell);
                float hy = gate * tanhf(cy);
                if (mode) ((float*)out)[idx] = hy;
                else      ((bf16*)out)[idx] = FB(hy);
            }
        }
    }
}

// ---------------------------------------------------------------------------
// Deformable conv1d local branch; bf16 out in (B,C,L) layout.
// ---------------------------------------------------------------------------
__launch_bounds__(256)
__global__ void deform_k(const void* __restrict__ xt, const bf16* __restrict__ wtb,
                         bf16* __restrict__ outL) {
    __shared__ __align__(16) u16 ot[128 * 72];
    __shared__ int s_fp[192], s_cp[192];
    __shared__ float s_al[192], s_mk[192];
    const int mode = get_mode(xt);
    const int tid = threadIdx.x;
    const int wave = tid >> 6, lane = tid & 63;
    const int b = blockIdx.x >> 6;
    const int l0 = (blockIdx.x & 63) << 6;
    float wo[3][3][2], wmk[3][3][2];
    #pragma unroll
    for (int k = 0; k < 3; ++k)
        #pragma unroll
        for (int j = 0; j < 3; ++j) {
            wo[k][j][0]  = BF(wtb[O_OW + (k * 128 + lane) * 3 + j]);
            wo[k][j][1]  = BF(wtb[O_OW + (k * 128 + lane + 64) * 3 + j]);
            wmk[k][j][0] = BF(wtb[O_MW + (k * 128 + lane) * 3 + j]);
            wmk[k][j][1] = BF(wtb[O_MW + (k * 128 + lane + 64) * 3 + j]);
        }
    for (int il = 0; il < 16; ++il) {
        int l_loc = wave * 16 + il;
        int l = l0 + l_loc;
        float a6[6] = {};
        #pragma unroll
        for (int j = 0; j < 3; ++j) {
            int row = l + j - 1;
            if (row >= 0 && row < 4096) {
                size_t base = ((size_t)(b << 12) + row) * 128;
                float x0 = LD(xt, base + lane, mode);
                float x1 = LD(xt, base + lane + 64, mode);
                #pragma unroll
                for (int k = 0; k < 3; ++k) {
                    a6[k]     += x0 * wo[k][j][0]  + x1 * wo[k][j][1];
                    a6[3 + k] += x0 * wmk[k][j][0] + x1 * wmk[k][j][1];
                }
            }
        }
        #pragma unroll
        for (int off = 32; off > 0; off >>= 1)
            #pragma unroll
            for (int k = 0; k < 6; ++k) a6[k] += __shfl_down(a6[k], off);
        if (lane == 0) {
            #pragma unroll
            for (int k = 0; k < 3; ++k) {
                float off = a6[k] + BF(wtb[O_OB + k]);
                float pos = fminf(fmaxf((float)l + off, 0.f), 4095.f);
                float fpf = floorf(pos);
                int fp = (int)fpf;
                int cp = fp + 1 > 4095 ? 4095 : fp + 1;
                s_fp[l_loc * 3 + k] = fp;
                s_cp[l_loc * 3 + k] = cp;
                s_al[l_loc * 3 + k] = pos - fpf;
                float mv = a6[3 + k] + BF(wtb[O_MB + k]);
                s_mk[l_loc * 3 + k] = 1.f / (1.f + expf(-mv));
            }
        }
    }
    __syncthreads();
    {
        int c = tid & 127, lh = tid >> 7;
        for (int it = 0; it < 32; ++it) {
            int l_loc = lh * 32 + it;
            float o = 0.f;
            #pragma unroll
            for (int k = 0; k < 3; ++k) {
                int fp = s_fp[l_loc * 3 + k];
                int cp = s_cp[l_loc * 3 + k];
                float al = s_al[l_loc * 3 + k];
                float mk = s_mk[l_loc * 3 + k];
                float xf = LD(xt, ((size_t)(b << 12) + fp) * 128 + c, mode);
                float xc = LD(xt, ((size_t)(b << 12) + cp) * 128 + c, mode);
                o += (xf * (1.f - al) + xc * al) * mk;
            }
            ot[c * 72 + l_loc] = FBu(o);
        }
    }
    __syncthreads();
    #pragma unroll
    for (int pass = 0; pass < 4; ++pass) {
        int cc = pass * 32 + (tid >> 3);
        int oo = tid & 7;
        const uint4 v = *(const uint4*)(ot + cc * 72 + oo * 8);
        *(uint4*)(outL + (size_t)b * 524288 + (size_t)cc * 4096 + l0 + oo * 8) = v;
    }
}

extern "C" void kernel_launch(void* const* d_in, const int* in_sizes, int n_in,
                              void* d_out, int out_size, void* d_ws, size_t ws_size,
                              hipStream_t stream) {
    (void)out_size; (void)ws_size;
    int I[28] = {0,1,2,3,4,5,6,7,8,9,10,11,12,13,14,15,16,17,18,19,20,21,22,23,24,25,26,27};
    if (n_in >= 28 && in_sizes[7] != 98304 && in_sizes[23] == 98304 && in_sizes[26] == 1800) {
        int alt[28] = {27, 9, 0, 25, 24, 15, 14, 23, 22, 26, 21, 20, 17, 16,
                       2, 1, 4, 3, 19, 18, 13, 12, 11, 10, 8, 7, 6, 5};
        for (int i = 0; i < 28; ++i) I[i] = alt[i];
    }
    const void* xt = d_in[I[0]];
    const void* hx = d_in[I[1]];
    const void* cx = d_in[I[2]];

    char* wsb = (char*)d_ws;
    float* g    = (float*)wsb;                    // fp32 residual [0,16M)
    u16*   Abf  = (u16*)(wsb + 16777216);         // bf16(g)
    u16*   Bbf  = (u16*)(wsb + 25165824);         // Xcat / qkv
    u16*   Cbf  = (u16*)(wsb + 50331648);         // attn-out / local
    bf16*  wtb  = (bf16*)(wsb + 58720256);
    u16*   wtu  = (u16*)wtb;

    Prep p;
    PrepT descs[29] = {
        {d_in[I[3]],  0,     256, 128, O_REDW},
        {d_in[I[7]],  0,     128, 384, O_QKVW},
        {d_in[I[7]],  49152, 128, 384, O_QKVW + 49152},
        {d_in[I[10]], 0,     128, 128, O_PW},
        {d_in[I[10]], 16384, 128, 128, O_PW + 16384},
        {d_in[I[14]], 0,     128, 512, O_F1W},
        {d_in[I[14]], 65536, 128, 512, O_F1W + 65536},
        {d_in[I[16]], 0,     512, 128, O_F2W},
        {d_in[I[16]], 65536, 512, 128, O_F2W + 65536},
        {d_in[I[22]], 0,     128, 128, O_LFW},
        {d_in[I[24]], 0,     128, 128, O_GFW},
        {d_in[I[26]], 0,     128, 128, O_FFW},
        {d_in[I[4]],  0,  128, 0, O_REDB},
        {d_in[I[8]],  0,  768, 0, O_QKVB},
        {d_in[I[11]], 0,  256, 0, O_PB},
        {d_in[I[15]], 0, 1024, 0, O_F1B},
        {d_in[I[17]], 0,  256, 0, O_F2B},
        {d_in[I[23]], 0,  128, 0, O_LFB},
        {d_in[I[25]], 0,  128, 0, O_GFB},
        {d_in[I[27]], 0,  128, 0, O_FFB},
        {d_in[I[9]],  0, 1800, 0, O_RP},
        {d_in[I[5]],  0,  256, 0, O_N1G},
        {d_in[I[6]],  0,  256, 0, O_N1B},
        {d_in[I[12]], 0,  256, 0, O_N2G},
        {d_in[I[13]], 0,  256, 0, O_N2B},
        {d_in[I[18]], 0, 1152, 0, O_OW},
        {d_in[I[19]], 0,    3, 0, O_OB},
        {d_in[I[20]], 0, 1152, 0, O_MW},
        {d_in[I[21]], 0,    3, 0, O_MB},
    };
    int cum = 0;
    for (int i = 0; i < 29; ++i) {
        p.d[i] = descs[i];
        p.start[i] = cum;
        cum += (descs[i].N > 0) ? descs[i].K * descs[i].N : descs[i].K;
    }
    p.start[29] = cum;

    prep_k<<<(cum + 255) / 256, 256, 0, stream>>>(p, wtb, xt);
    xcat_k<<<1024, 256, 0, stream>>>(xt, hx, Bbf);

    // g = Xcat @ red_w + red_b (fp32)
    gemm_mfma<5><<<dim3(1, 256), 256, 0, stream>>>(Bbf, wtu + O_REDW, wtb + O_REDB,
                                                   nullptr, g, 32768, 128, 256, 0);

    for (int d = 0; d < 2; ++d) {
        int shift = d ? 4 : 0;
        qkvln_k<<<256, 256, 0, stream>>>(g, wtu, wtb, Bbf, d, shift);
        attn_k<<<512, 256, 0, stream>>>(Bbf, wtb + O_RP + d * 900, Cbf, shift);
        gemm_mfma<3><<<dim3(1, 256), 256, 0, stream>>>(Cbf, wtu + O_PW + d * 16384,
                                                       wtb + O_PB + d * 128, nullptr, g,
                                                       32768, 128, 128, shift);
        mlp_k<<<256, 256, 0, stream>>>(g, (bf16*)Abf, wtu, wtb, d);
    }

    // local branch -> Cbf (B,C,L)
    deform_k<<<512, 256, 0, stream>>>(xt, wtb, (bf16*)Cbf);
    // fused fusion chain + LSTM -> out
    fuse3_k<<<256, 256, 0, stream>>>(Cbf, Abf, wtu, wtb, cx, d_out, xt);
}

// Round 7
// 451.251 us; speedup vs baseline: 2.5854x; 1.1014x over previous
//
#include <hip/hip_runtime.h>
#include <hip/hip_bf16.h>
#include <math.h>

typedef __hip_bfloat16 bf16;
typedef unsigned short u16;
#define BF(x) __bfloat162float(x)
static __device__ __forceinline__ bf16 FB(float x) { return __float2bfloat16(x); }
static __device__ __forceinline__ u16 FBu(float x) {
    bf16 b = __float2bfloat16(x);
    return *(u16*)&b;
}

typedef __attribute__((ext_vector_type(4))) float f32x4;
typedef __attribute__((ext_vector_type(8))) __bf16 bf16x8;

// Problem: B=8, H=W=64, C=128, L=4096, NH=4, HD=32, WIN=8, N=64, NW=64, M=32768.

// Wt (prepped bf16 weights) element offsets
#define O_REDW 0
#define O_QKVW 32768
#define O_PW   131072
#define O_F1W  163840
#define O_F2W  294912
#define O_LFW  425984
#define O_GFW  442368
#define O_FFW  458752
#define O_REDB 475136
#define O_QKVB 475264
#define O_PB   476032
#define O_F1B  476288
#define O_F2B  477312
#define O_LFB  477568
#define O_GFB  477696
#define O_FFB  477824
#define O_RP   477952
#define O_N1G  479752
#define O_N1B  480008
#define O_N2G  480264
#define O_N2B  480520
#define O_OW   480776
#define O_OB   481928
#define O_MW   481931
#define O_MB   483083

// Padded LDS tile geometry for VALU-written A-tiles (kills 16-way conflicts):
// row stride 36 u16 (72 B = 18 banks), chunk stride 2320 u16.
#define ROW_S 36
#define CH_S  2320

// Runtime input-dtype detection from xt (N(0,1) data). 0 = bf16, 1 = fp32.
__device__ __forceinline__ int get_mode(const void* xt) {
    const unsigned* w = (const unsigned*)xt;
    int zlo = 0, inband = 0;
    #pragma unroll
    for (int i = 0; i < 32; ++i) {
        unsigned lo = w[i] & 0xFFFFu;
        int e = (int)((lo >> 7) & 0xFF);
        zlo += (lo == 0u || lo == 0x8000u);
        inband += (e >= 100 && e <= 140);
    }
    if (zlo >= 29) return 1;
    return (inband >= 20) ? 0 : 1;
}

__device__ __forceinline__ float LD(const void* p, size_t i, int mode) {
    return mode ? ((const float*)p)[i] : BF(((const bf16*)p)[i]);
}

// async global->LDS, 16 bytes per lane
__device__ __forceinline__ void async16(const u16* g, u16* l) {
    __builtin_amdgcn_global_load_lds(
        (const __attribute__((address_space(1))) unsigned int*)g,
        (__attribute__((address_space(3))) unsigned int*)l, 16, 0, 0);
}

// ---------------------------------------------------------------------------
// Prep: transpose weights to [N][K] bf16 + convert params.
// ---------------------------------------------------------------------------
struct PrepT { const void* src; int srcOff, K, N, dstOff; };
struct Prep { PrepT d[29]; int start[30]; };

__global__ void prep_k(Prep p, bf16* __restrict__ dst, const void* __restrict__ dtp) {
    const int mode = get_mode(dtp);
    int i = blockIdx.x * 256 + threadIdx.x;
    if (i >= p.start[29]) return;
    int s = 0;
    while (p.start[s + 1] <= i) ++s;
    int e = i - p.start[s];
    float v;
    if (p.d[s].N > 0) {
        int n = e / p.d[s].K, k = e % p.d[s].K;
        v = LD(p.d[s].src, (size_t)p.d[s].srcOff + (size_t)k * p.d[s].N + n, mode);
    } else {
        v = LD(p.d[s].src, (size_t)p.d[s].srcOff + e, mode);
    }
    dst[p.d[s].dstOff + e] = FB(v);
}

// Vectorized concat: X[32768][256] = bf16([xt | hx]).  Grid-stride.
__launch_bounds__(256)
__global__ void xcat_k(const void* __restrict__ xt, const void* __restrict__ hx,
                       u16* __restrict__ X) {
    const int mode = get_mode(xt);
    const int total = 32768 * 32;            // groups of 8 elements
    for (int gidx = blockIdx.x * 256 + threadIdx.x; gidx < total;
         gidx += gridDim.x * 256) {
        int r = gidx >> 5, gi = gidx & 31;
        const void* src = (gi < 16) ? xt : hx;
        int c = (gi & 15) << 3;
        u16 outv[8];
        if (mode) {
            const float* s = (const float*)src + (size_t)r * 128 + c;
            float4 a = *(const float4*)s;
            float4 b = *(const float4*)(s + 4);
            outv[0] = FBu(a.x); outv[1] = FBu(a.y); outv[2] = FBu(a.z); outv[3] = FBu(a.w);
            outv[4] = FBu(b.x); outv[5] = FBu(b.y); outv[6] = FBu(b.z); outv[7] = FBu(b.w);
        } else {
            *(uint4*)outv = *(const uint4*)((const u16*)src + (size_t)r * 128 + c);
        }
        *(uint4*)(X + (size_t)r * 256 + (gi << 3)) = *(const uint4*)outv;
    }
}

// ---------------------------------------------------------------------------
// MFMA GEMM 128x128 tile, BK=32. EPI 3: window-reverse/roll scatter-add into
// outf. 5: fp32 store.
// ---------------------------------------------------------------------------
template <int EPI>
__launch_bounds__(256)
__global__ void gemm_mfma(const u16* __restrict__ A, const u16* __restrict__ Bt,
                          const bf16* __restrict__ bias, bf16* __restrict__ outb,
                          float* __restrict__ outf, int M, int N, int K, int shift) {
    __shared__ __align__(16) u16 Als[4096];
    __shared__ __align__(16) u16 Bls[4096];
    const int tid = threadIdx.x;
    const int wave = tid >> 6, lane = tid & 63;
    const int q = lane >> 4, lr = lane & 15;
    const int wm = (wave >> 1) << 6, wn = (wave & 1) << 6;
    const int bm = blockIdx.y << 7, bn = blockIdx.x << 7;
    const f32x4 zero = {0.f, 0.f, 0.f, 0.f};
    f32x4 acc[4][4];
    #pragma unroll
    for (int i = 0; i < 4; ++i)
        #pragma unroll
        for (int j = 0; j < 4; ++j) acc[i][j] = zero;

    for (int k0 = 0; k0 < K; k0 += 32) {
        #pragma unroll
        for (int c = tid; c < 512; c += 256) {
            async16(A + (size_t)(bm + (c >> 2)) * K + k0 + ((c & 3) << 3), Als + (c << 3));
            async16(Bt + (size_t)(bn + (c >> 2)) * K + k0 + ((c & 3) << 3), Bls + (c << 3));
        }
        __syncthreads();
        bf16x8 af[4], bfr[4];
        #pragma unroll
        for (int t = 0; t < 4; ++t) {
            af[t]  = *(const bf16x8*)(Als + ((wm + (t << 4) + lr) << 5) + (q << 3));
            bfr[t] = *(const bf16x8*)(Bls + ((wn + (t << 4) + lr) << 5) + (q << 3));
        }
        #pragma unroll
        for (int mt = 0; mt < 4; ++mt)
            #pragma unroll
            for (int nt = 0; nt < 4; ++nt)
                acc[mt][nt] = __builtin_amdgcn_mfma_f32_16x16x32_bf16(
                    af[mt], bfr[nt], acc[mt][nt], 0, 0, 0);
        __syncthreads();
    }

    #pragma unroll
    for (int nt = 0; nt < 4; ++nt) {
        int col = bn + wn + (nt << 4) + lr;
        float bv = BF(bias[col]);
        #pragma unroll
        for (int mt = 0; mt < 4; ++mt) {
            int row0 = bm + wm + (mt << 4) + (q << 2);
            #pragma unroll
            for (int i = 0; i < 4; ++i) {
                int r = row0 + i;
                float v = acc[mt][nt][i] + bv;
                size_t idx = (size_t)r * N + col;
                if (EPI == 0) {
                    outb[idx] = FB(v);
                } else if (EPI == 3) {
                    int b = r >> 12, rem = r & 4095;
                    int wi = rem >> 6, n = rem & 63;
                    int hp = ((wi >> 3) << 3) + (n >> 3);
                    int wp = ((wi & 7) << 3) + (n & 7);
                    int h = (hp + shift) & 63, w = (wp + shift) & 63;
                    outf[((size_t)((b << 12) + (h << 6) + w)) * 128 + col] += v;
                } else if (EPI == 5) {
                    outf[idx] = v;
                }
            }
        }
    }
}

// ---------------------------------------------------------------------------
// Fused LN1 (+roll+window gather) + QKV GEMM. Block = 64 windowed rows,
// 512 blocks. LDS: Ach 4x[64][36] padded | Bb 4x[128][32] (async16-staged).
// ---------------------------------------------------------------------------
__launch_bounds__(256)
__global__ void qkvln_k(const float* __restrict__ g, const u16* __restrict__ wtu,
                        const bf16* __restrict__ wtb, u16* __restrict__ qkv,
                        int d, int shift) {
    __shared__ __align__(16) u16 Ach[4 * CH_S];
    __shared__ __align__(16) u16 Bb[16384];
    const int tid = threadIdx.x;
    const int wave = tid >> 6, lane = tid & 63;
    const int q = lane >> 4, lr = lane & 15;
    const int wm = (wave >> 1) << 5, wn = (wave & 1) << 6;
    const int bm = blockIdx.x << 6;

    // LN1 with inverse-roll gather: thread = (row = tid>>2, qtr = tid&3)
    {
        int row = tid >> 2, qtr = tid & 3;
        int r = bm + row;
        int b = r >> 12, rem = r & 4095;
        int wi = rem >> 6, n = rem & 63;
        int hp = ((wi >> 3) << 3) + (n >> 3);
        int wp = ((wi & 7) << 3) + (n & 7);
        int h = (hp + shift) & 63, w = (wp + shift) & 63;
        int src = (b << 12) + (h << 6) + w;
        const float* gr = g + (size_t)src * 128 + qtr * 32;
        float vals[32];
        float s1 = 0.f, s2 = 0.f;
        #pragma unroll
        for (int i = 0; i < 8; ++i) {
            float4 v4 = *(const float4*)(gr + i * 4);
            vals[i * 4] = v4.x; vals[i * 4 + 1] = v4.y;
            vals[i * 4 + 2] = v4.z; vals[i * 4 + 3] = v4.w;
            s1 += v4.x + v4.y + v4.z + v4.w;
            s2 += v4.x * v4.x + v4.y * v4.y + v4.z * v4.z + v4.w * v4.w;
        }
        s1 += __shfl_xor(s1, 1); s1 += __shfl_xor(s1, 2);
        s2 += __shfl_xor(s2, 1); s2 += __shfl_xor(s2, 2);
        float mu = s1 * (1.f / 128.f);
        float var = s2 * (1.f / 128.f) - mu * mu;
        float inv = rsqrtf(var + 1e-5f);
        #pragma unroll
        for (int i = 0; i < 32; ++i) {
            int c = qtr * 32 + i;
            float o = (vals[i] - mu) * inv * BF(wtb[O_N1G + d * 128 + c])
                      + BF(wtb[O_N1B + d * 128 + c]);
            Ach[qtr * CH_S + row * ROW_S + i] = FBu(o);
        }
    }
    __syncthreads();

    const f32x4 zero = {0.f, 0.f, 0.f, 0.f};
    for (int nc = 0; nc < 3; ++nc) {
        const u16* Bg = wtu + O_QKVW + d * 49152 + nc * 16384;
        #pragma unroll
        for (int i = tid; i < 2048; i += 256) {
            int kc = i >> 9, c = i & 511;
            async16(Bg + (size_t)(c >> 2) * 128 + (kc << 5) + ((c & 3) << 3),
                    Bb + (kc << 12) + (c << 3));
        }
        __syncthreads();
        f32x4 acc[2][4];
        #pragma unroll
        for (int i = 0; i < 2; ++i)
            #pragma unroll
            for (int j = 0; j < 4; ++j) acc[i][j] = zero;
        #pragma unroll
        for (int k0 = 0; k0 < 4; ++k0) {
            bf16x8 af[2], bfr[4];
            #pragma unroll
            for (int t = 0; t < 2; ++t)
                af[t] = *(const bf16x8*)(Ach + k0 * CH_S + (wm + (t << 4) + lr) * ROW_S + (q << 3));
            #pragma unroll
            for (int t = 0; t < 4; ++t)
                bfr[t] = *(const bf16x8*)(Bb + (k0 << 12) + ((wn + (t << 4) + lr) << 5) + (q << 3));
            #pragma unroll
            for (int mt = 0; mt < 2; ++mt)
                #pragma unroll
                for (int nt = 0; nt < 4; ++nt)
                    acc[mt][nt] = __builtin_amdgcn_mfma_f32_16x16x32_bf16(
                        af[mt], bfr[nt], acc[mt][nt], 0, 0, 0);
        }
        #pragma unroll
        for (int nt = 0; nt < 4; ++nt) {
            int col = wn + (nt << 4) + lr;
            float bv = BF(wtb[O_QKVB + d * 384 + nc * 128 + col]);
            #pragma unroll
            for (int mt = 0; mt < 2; ++mt) {
                #pragma unroll
                for (int i = 0; i < 4; ++i) {
                    int r = bm + wm + (mt << 4) + (q << 2) + i;
                    qkv[(size_t)r * 384 + nc * 128 + col] = FBu(acc[mt][nt][i] + bv);
                }
            }
        }
        __syncthreads();
    }
}

// ---------------------------------------------------------------------------
// Windowed attention: block = one window (4 heads = 4 waves).
// ---------------------------------------------------------------------------
__launch_bounds__(256)
__global__ void attn_k(const u16* __restrict__ qkv, const bf16* __restrict__ rp,
                       u16* __restrict__ outp, int shift) {
    __shared__ float kT[4][32][64];
    __shared__ float vT[4][32][64];
    const int wq = blockIdx.x;
    const int head = threadIdx.x >> 6;
    const int t = threadIdx.x & 63;
    const size_t rbase = (size_t)(wq * 64 + t) * 384 + head * 32;
    float q[32];
    #pragma unroll
    for (int j = 0; j < 4; ++j) {
        bf16x8 qv = *(const bf16x8*)(qkv + rbase + j * 8);
        bf16x8 kv = *(const bf16x8*)(qkv + rbase + 128 + j * 8);
        bf16x8 vv = *(const bf16x8*)(qkv + rbase + 256 + j * 8);
        #pragma unroll
        for (int e = 0; e < 8; ++e) {
            int dd = j * 8 + e;
            q[dd] = (float)qv[e] * 0.17677669529663687f;
            kT[head][dd][t] = (float)kv[e];
            vT[head][dd][t] = (float)vv[e];
        }
    }
    __syncthreads();
    const int wloc = wq & 63;
    const int wh = (wloc >> 3) << 3, wwb = (wloc & 7) << 3;
    int regt = 0;
    if (shift) {
        int hp = wh + (t >> 3), wp = wwb + (t & 7);
        int rh = hp < 56 ? 0 : (hp < 60 ? 1 : 2);
        int rw = wp < 56 ? 0 : (wp < 60 ? 1 : 2);
        regt = rh * 3 + rw;
    }
    const int ti = t >> 3, tj = t & 7;
    float s[64];
    float mx = -1e30f;
    #pragma unroll
    for (int m = 0; m < 64; ++m) {
        float acc = 0.f;
        #pragma unroll
        for (int dd = 0; dd < 32; ++dd) acc += q[dd] * kT[head][dd][m];
        int idx = (ti - (m >> 3) + 7) * 15 + (tj - (m & 7) + 7);
        acc += BF(rp[idx * 4 + head]);
        if (shift) {
            int hp = wh + (m >> 3), wp = wwb + (m & 7);
            int rh = hp < 56 ? 0 : (hp < 60 ? 1 : 2);
            int rw = wp < 56 ? 0 : (wp < 60 ? 1 : 2);
            if (regt != rh * 3 + rw) acc -= 100.f;
        }
        s[m] = acc;
        mx = fmaxf(mx, acc);
    }
    float l = 0.f;
    #pragma unroll
    for (int m = 0; m < 64; ++m) {
        s[m] = expf(s[m] - mx);
        l += s[m];
    }
    const float inv = 1.f / l;
    const size_t obase = (size_t)(wq * 64 + t) * 128 + head * 32;
    #pragma unroll
    for (int j = 0; j < 4; ++j) {
        bf16x8 ov;
        #pragma unroll
        for (int e = 0; e < 8; ++e) {
            int dd = j * 8 + e;
            float a = 0.f;
            #pragma unroll
            for (int m = 0; m < 64; ++m) a += s[m] * vT[head][dd][m];
            ov[e] = (__bf16)(a * inv);
        }
        *(bf16x8*)(outp + obase + j * 8) = ov;
    }
}

// ---------------------------------------------------------------------------
// Fused MLP: LN2 + f1 + GELU + f2 + residual into g (+ bf16 copy to gbf).
// Block = 64 rows, 512 blocks. LDS: Ach 4x[64][36] | buf1 16KB | buf2 2x[64][36].
// ---------------------------------------------------------------------------
__launch_bounds__(256)
__global__ void mlp_k(float* __restrict__ g, bf16* __restrict__ gbf,
                      const u16* __restrict__ wtu, const bf16* __restrict__ wtb,
                      int d) {
    __shared__ __align__(16) u16 Ach[4 * CH_S];
    __shared__ __align__(16) u16 buf1[8192];
    __shared__ __align__(16) u16 buf2[2 * CH_S];
    const int tid = threadIdx.x;
    const int wave = tid >> 6, lane = tid & 63;
    const int q = lane >> 4, lr = lane & 15;
    const int wm = (wave >> 1) << 5;   // 0 / 32 (row split)
    const int wn0 = (wave & 1) << 5;   // stage1: 32-hcol split
    const int wn = (wave & 1) << 6;    // stage2: 64-ncol split
    const int bm = blockIdx.x << 6;

    // LN2: thread = (row = tid>>2, qtr = tid&3)
    {
        int row = tid >> 2, qtr = tid & 3;
        const float* gr = g + (size_t)(bm + row) * 128 + qtr * 32;
        float vals[32];
        float s1 = 0.f, s2 = 0.f;
        #pragma unroll
        for (int i = 0; i < 8; ++i) {
            float4 v4 = *(const float4*)(gr + i * 4);
            vals[i * 4] = v4.x; vals[i * 4 + 1] = v4.y;
            vals[i * 4 + 2] = v4.z; vals[i * 4 + 3] = v4.w;
            s1 += v4.x + v4.y + v4.z + v4.w;
            s2 += v4.x * v4.x + v4.y * v4.y + v4.z * v4.z + v4.w * v4.w;
        }
        s1 += __shfl_xor(s1, 1); s1 += __shfl_xor(s1, 2);
        s2 += __shfl_xor(s2, 1); s2 += __shfl_xor(s2, 2);
        float mu = s1 * (1.f / 128.f);
        float var = s2 * (1.f / 128.f) - mu * mu;
        float inv = rsqrtf(var + 1e-5f);
        #pragma unroll
        for (int i = 0; i < 32; ++i) {
            int c = qtr * 32 + i;
            float o = (vals[i] - mu) * inv * BF(wtb[O_N2G + d * 128 + c])
                      + BF(wtb[O_N2B + d * 128 + c]);
            Ach[qtr * CH_S + row * ROW_S + i] = FBu(o);
        }
    }
    __syncthreads();

    const f32x4 zero = {0.f, 0.f, 0.f, 0.f};
    f32x4 acc2[2][4];
    #pragma unroll
    for (int i = 0; i < 2; ++i)
        #pragma unroll
        for (int j = 0; j < 4; ++j) acc2[i][j] = zero;

    for (int h = 0; h < 8; ++h) {
        // stage B1 chunk: 64 hcols x 128 K -> 4 chunks [64][32] in buf1
        const u16* B1g = wtu + O_F1W + d * 65536 + h * 8192;
        #pragma unroll
        for (int i = tid; i < 1024; i += 256) {
            int kc = i >> 8, c = i & 255;
            async16(B1g + (c >> 2) * 128 + (kc << 5) + ((c & 3) << 3),
                    buf1 + (kc << 11) + (c << 3));
        }
        __syncthreads();
        f32x4 acc1[2][2];
        #pragma unroll
        for (int i = 0; i < 2; ++i) { acc1[i][0] = zero; acc1[i][1] = zero; }
        #pragma unroll
        for (int k0 = 0; k0 < 4; ++k0) {
            bf16x8 af[2], bfr[2];
            #pragma unroll
            for (int t = 0; t < 2; ++t) {
                af[t]  = *(const bf16x8*)(Ach + k0 * CH_S + (wm + (t << 4) + lr) * ROW_S + (q << 3));
                bfr[t] = *(const bf16x8*)(buf1 + (k0 << 11) + ((wn0 + (t << 4) + lr) << 5) + (q << 3));
            }
            #pragma unroll
            for (int mt = 0; mt < 2; ++mt)
                #pragma unroll
                for (int nt = 0; nt < 2; ++nt)
                    acc1[mt][nt] = __builtin_amdgcn_mfma_f32_16x16x32_bf16(
                        af[mt], bfr[nt], acc1[mt][nt], 0, 0, 0);
        }
        // GELU -> hidden chunks (padded) in buf2
        #pragma unroll
        for (int nt = 0; nt < 2; ++nt) {
            int c = wn0 + (nt << 4) + lr;
            float hb = BF(wtb[O_F1B + d * 512 + h * 64 + c]);
            #pragma unroll
            for (int mt = 0; mt < 2; ++mt) {
                #pragma unroll
                for (int i = 0; i < 4; ++i) {
                    int r = wm + (mt << 4) + (q << 2) + i;
                    float v = acc1[mt][nt][i] + hb;
                    float ge = 0.5f * v * (1.0f + erff(v * 0.70710678118654752f));
                    buf2[(c >> 5) * CH_S + r * ROW_S + (c & 31)] = FBu(ge);
                }
            }
        }
        __syncthreads();
        // stage B2 chunk: 128 ncols x 64 K -> 2 chunks [128][32] in buf1
        const u16* B2g = wtu + O_F2W + d * 65536 + h * 64;
        #pragma unroll
        for (int i = tid; i < 1024; i += 256) {
            int kc = i >> 9, c = i & 511;
            async16(B2g + (size_t)(c >> 2) * 512 + (kc << 5) + ((c & 3) << 3),
                    buf1 + (kc << 12) + (c << 3));
        }
        __syncthreads();
        #pragma unroll
        for (int kc = 0; kc < 2; ++kc) {
            bf16x8 ah[2], b2[4];
            #pragma unroll
            for (int t = 0; t < 2; ++t)
                ah[t] = *(const bf16x8*)(buf2 + kc * CH_S + (wm + (t << 4) + lr) * ROW_S + (q << 3));
            #pragma unroll
            for (int t = 0; t < 4; ++t)
                b2[t] = *(const bf16x8*)(buf1 + (kc << 12) + ((wn + (t << 4) + lr) << 5) + (q << 3));
            #pragma unroll
            for (int mt = 0; mt < 2; ++mt)
                #pragma unroll
                for (int nt = 0; nt < 4; ++nt)
                    acc2[mt][nt] = __builtin_amdgcn_mfma_f32_16x16x32_bf16(
                        ah[mt], b2[nt], acc2[mt][nt], 0, 0, 0);
        }
        __syncthreads();
    }
    #pragma unroll
    for (int nt = 0; nt < 4; ++nt) {
        int col = wn + (nt << 4) + lr;
        float bv = BF(wtb[O_F2B + d * 128 + col]);
        #pragma unroll
        for (int mt = 0; mt < 2; ++mt) {
            #pragma unroll
            for (int i = 0; i < 4; ++i) {
                int r = bm + wm + (mt << 4) + (q << 2) + i;
                size_t idx = (size_t)r * 128 + col;
                float nv = g[idx] + acc2[mt][nt][i] + bv;
                g[idx] = nv;
                gbf[idx] = FB(nv);
            }
        }
    }
}

// ---------------------------------------------------------------------------
// Fused fusion chain + LSTM gate -> out.
// ---------------------------------------------------------------------------
__launch_bounds__(256)
__global__ void fuse3_k(const u16* __restrict__ Aloc, const u16* __restrict__ Ag,
                        const u16* __restrict__ wtu, const bf16* __restrict__ wtb,
                        const void* __restrict__ cx, void* __restrict__ out,
                        const void* __restrict__ dtp) {
    __shared__ __align__(16) u16 sm[32768];
    u16* sA  = sm;
    u16* sG  = sm + 4096;
    u16* sLF = sm + 8192;
    u16* sGF = sm + 12288;
    u16* relb = sm + 16384;
    const int mode = get_mode(dtp);
    const int tid = threadIdx.x;
    const int wave = tid >> 6, lane = tid & 63;
    const int q = lane >> 4, lr = lane & 15;
    const int wm = (wave >> 1) << 6, wn = (wave & 1) << 6;
    const int bm = blockIdx.x << 7;
    const f32x4 zero = {0.f, 0.f, 0.f, 0.f};
    f32x4 acc1[4][4], acc2[4][4];
    #pragma unroll
    for (int i = 0; i < 4; ++i)
        #pragma unroll
        for (int j = 0; j < 4; ++j) { acc1[i][j] = zero; acc2[i][j] = zero; }

    #pragma unroll
    for (int k0 = 0; k0 < 4; ++k0) {
        #pragma unroll
        for (int i = tid; i < 512; i += 256) {
            int ld = i & 63, r0 = (i >> 6) << 4;
            int row = r0 + (ld >> 2), sub = (ld & 3) << 3;
            int dstoff = (r0 << 5) + (ld << 3);
            async16(Aloc + (size_t)(bm + row) * 128 + (k0 << 5) + sub, sA + dstoff);
            async16(Ag   + (size_t)(bm + row) * 128 + (k0 << 5) + sub, sG + dstoff);
            async16(wtu + O_LFW + row * 128 + (k0 << 5) + sub, sLF + dstoff);
            async16(wtu + O_GFW + row * 128 + (k0 << 5) + sub, sGF + dstoff);
        }
        __syncthreads();
        bf16x8 al[4], ag[4], blf[4], bgf[4];
        #pragma unroll
        for (int t = 0; t < 4; ++t) {
            int ro = ((wm + (t << 4) + lr) << 5) + (q << 3);
            int co = ((wn + (t << 4) + lr) << 5) + (q << 3);
            al[t]  = *(const bf16x8*)(sA + ro);
            ag[t]  = *(const bf16x8*)(sG + ro);
            blf[t] = *(const bf16x8*)(sLF + co);
            bgf[t] = *(const bf16x8*)(sGF + co);
        }
        #pragma unroll
        for (int mt = 0; mt < 4; ++mt)
            #pragma unroll
            for (int nt = 0; nt < 4; ++nt) {
                acc1[mt][nt] = __builtin_amdgcn_mfma_f32_16x16x32_bf16(
                    al[mt], blf[nt], acc1[mt][nt], 0, 0, 0);
                acc2[mt][nt] = __builtin_amdgcn_mfma_f32_16x16x32_bf16(
                    ag[mt], bgf[nt], acc2[mt][nt], 0, 0, 0);
            }
        __syncthreads();
    }
    #pragma unroll
    for (int nt = 0; nt < 4; ++nt) {
        int c = wn + (nt << 4) + lr;
        float lfb = BF(wtb[O_LFB + c]);
        float gfb = BF(wtb[O_GFB + c]);
        #pragma unroll
        for (int mt = 0; mt < 4; ++mt) {
            #pragma unroll
            for (int i = 0; i < 4; ++i) {
                int r = wm + (mt << 4) + (q << 2) + i;
                float t1 = acc1[mt][nt][i] + lfb;
                float t2 = acc2[mt][nt][i] + gfb;
                float rel = t1 * t2;
                relb[((c >> 5) << 12) + (r << 5) + (c & 31)] = FBu(rel > 0.f ? rel : 0.f);
            }
        }
    }
    __syncthreads();
    f32x4 acc3[4][4];
    #pragma unroll
    for (int i = 0; i < 4; ++i)
        #pragma unroll
        for (int j = 0; j < 4; ++j) acc3[i][j] = zero;
    #pragma unroll
    for (int k0 = 0; k0 < 4; ++k0) {
        #pragma unroll
        for (int i = tid; i < 512; i += 256) {
            int ld = i & 63, r0 = (i >> 6) << 4;
            int row = r0 + (ld >> 2), sub = (ld & 3) << 3;
            async16(wtu + O_FFW + row * 128 + (k0 << 5) + sub, sA + (r0 << 5) + (ld << 3));
        }
        __syncthreads();
        bf16x8 ar[4], bff[4];
        #pragma unroll
        for (int t = 0; t < 4; ++t) {
            ar[t]  = *(const bf16x8*)(relb + (k0 << 12) + ((wm + (t << 4) + lr) << 5) + (q << 3));
            bff[t] = *(const bf16x8*)(sA + ((wn + (t << 4) + lr) << 5) + (q << 3));
        }
        #pragma unroll
        for (int mt = 0; mt < 4; ++mt)
            #pragma unroll
            for (int nt = 0; nt < 4; ++nt)
                acc3[mt][nt] = __builtin_amdgcn_mfma_f32_16x16x32_bf16(
                    ar[mt], bff[nt], acc3[mt][nt], 0, 0, 0);
        __syncthreads();
    }
    #pragma unroll
    for (int nt = 0; nt < 4; ++nt) {
        int col = wn + (nt << 4) + lr;
        float ffb = BF(wtb[O_FFB + col]);
        #pragma unroll
        for (int mt = 0; mt < 4; ++mt) {
            #pragma unroll
            for (int i = 0; i < 4; ++i) {
                int r = bm + wm + (mt << 4) + (q << 2) + i;
                size_t idx = (size_t)r * 128 + col;
                float v = acc3[mt][nt][i] + ffb;
                float gate = 1.f / (1.f + expf(-v));
                float cell = tanhf(v);
                float cy = gate * (LD(cx, idx, mode) + cell);
                float hy = gate * tanhf(cy);
                if (mode) ((float*)out)[idx] = hy;
                else      ((bf16*)out)[idx] = FB(hy);
            }
        }
    }
}

// ---------------------------------------------------------------------------
// Deformable conv1d local branch; bf16 out in (B,C,L) layout.
// ---------------------------------------------------------------------------
__launch_bounds__(256)
__global__ void deform_k(const void* __restrict__ xt, const bf16* __restrict__ wtb,
                         bf16* __restrict__ outL) {
    __shared__ __align__(16) u16 ot[128 * 72];
    __shared__ int s_fp[192], s_cp[192];
    __shared__ float s_al[192], s_mk[192];
    const int mode = get_mode(xt);
    const int tid = threadIdx.x;
    const int wave = tid >> 6, lane = tid & 63;
    const int b = blockIdx.x >> 6;
    const int l0 = (blockIdx.x & 63) << 6;
    float wo[3][3][2], wmk[3][3][2];
    #pragma unroll
    for (int k = 0; k < 3; ++k)
        #pragma unroll
        for (int j = 0; j < 3; ++j) {
            wo[k][j][0]  = BF(wtb[O_OW + (k * 128 + lane) * 3 + j]);
            wo[k][j][1]  = BF(wtb[O_OW + (k * 128 + lane + 64) * 3 + j]);
            wmk[k][j][0] = BF(wtb[O_MW + (k * 128 + lane) * 3 + j]);
            wmk[k][j][1] = BF(wtb[O_MW + (k * 128 + lane + 64) * 3 + j]);
        }
    for (int il = 0; il < 16; ++il) {
        int l_loc = wave * 16 + il;
        int l = l0 + l_loc;
        float a6[6] = {};
        #pragma unroll
        for (int j = 0; j < 3; ++j) {
            int row = l + j - 1;
            if (row >= 0 && row < 4096) {
                size_t base = ((size_t)(b << 12) + row) * 128;
                float x0 = LD(xt, base + lane, mode);
                float x1 = LD(xt, base + lane + 64, mode);
                #pragma unroll
                for (int k = 0; k < 3; ++k) {
                    a6[k]     += x0 * wo[k][j][0]  + x1 * wo[k][j][1];
                    a6[3 + k] += x0 * wmk[k][j][0] + x1 * wmk[k][j][1];
                }
            }
        }
        #pragma unroll
        for (int off = 32; off > 0; off >>= 1)
            #pragma unroll
            for (int k = 0; k < 6; ++k) a6[k] += __shfl_down(a6[k], off);
        if (lane == 0) {
            #pragma unroll
            for (int k = 0; k < 3; ++k) {
                float off = a6[k] + BF(wtb[O_OB + k]);
                float pos = fminf(fmaxf((float)l + off, 0.f), 4095.f);
                float fpf = floorf(pos);
                int fp = (int)fpf;
                int cp = fp + 1 > 4095 ? 4095 : fp + 1;
                s_fp[l_loc * 3 + k] = fp;
                s_cp[l_loc * 3 + k] = cp;
                s_al[l_loc * 3 + k] = pos - fpf;
                float mv = a6[3 + k] + BF(wtb[O_MB + k]);
                s_mk[l_loc * 3 + k] = 1.f / (1.f + expf(-mv));
            }
        }
    }
    __syncthreads();
    {
        int c = tid & 127, lh = tid >> 7;
        for (int it = 0; it < 32; ++it) {
            int l_loc = lh * 32 + it;
            float o = 0.f;
            #pragma unroll
            for (int k = 0; k < 3; ++k) {
                int fp = s_fp[l_loc * 3 + k];
                int cp = s_cp[l_loc * 3 + k];
                float al = s_al[l_loc * 3 + k];
                float mk = s_mk[l_loc * 3 + k];
                float xf = LD(xt, ((size_t)(b << 12) + fp) * 128 + c, mode);
                float xc = LD(xt, ((size_t)(b << 12) + cp) * 128 + c, mode);
                o += (xf * (1.f - al) + xc * al) * mk;
            }
            ot[c * 72 + l_loc] = FBu(o);
        }
    }
    __syncthreads();
    #pragma unroll
    for (int pass = 0; pass < 4; ++pass) {
        int cc = pass * 32 + (tid >> 3);
        int oo = tid & 7;
        const uint4 v = *(const uint4*)(ot + cc * 72 + oo * 8);
        *(uint4*)(outL + (size_t)b * 524288 + (size_t)cc * 4096 + l0 + oo * 8) = v;
    }
}

extern "C" void kernel_launch(void* const* d_in, const int* in_sizes, int n_in,
                              void* d_out, int out_size, void* d_ws, size_t ws_size,
                              hipStream_t stream) {
    (void)out_size; (void)ws_size;
    int I[28] = {0,1,2,3,4,5,6,7,8,9,10,11,12,13,14,15,16,17,18,19,20,21,22,23,24,25,26,27};
    if (n_in >= 28 && in_sizes[7] != 98304 && in_sizes[23] == 98304 && in_sizes[26] == 1800) {
        int alt[28] = {27, 9, 0, 25, 24, 15, 14, 23, 22, 26, 21, 20, 17, 16,
                       2, 1, 4, 3, 19, 18, 13, 12, 11, 10, 8, 7, 6, 5};
        for (int i = 0; i < 28; ++i) I[i] = alt[i];
    }
    const void* xt = d_in[I[0]];
    const void* hx = d_in[I[1]];
    const void* cx = d_in[I[2]];

    char* wsb = (char*)d_ws;
    float* g    = (float*)wsb;                    // fp32 residual [0,16M)
    u16*   Abf  = (u16*)(wsb + 16777216);         // bf16(g)
    u16*   Bbf  = (u16*)(wsb + 25165824);         // Xcat / qkv
    u16*   Cbf  = (u16*)(wsb + 50331648);         // attn-out / local
    bf16*  wtb  = (bf16*)(wsb + 58720256);
    u16*   wtu  = (u16*)wtb;

    Prep p;
    PrepT descs[29] = {
        {d_in[I[3]],  0,     256, 128, O_REDW},
        {d_in[I[7]],  0,     128, 384, O_QKVW},
        {d_in[I[7]],  49152, 128, 384, O_QKVW + 49152},
        {d_in[I[10]], 0,     128, 128, O_PW},
        {d_in[I[10]], 16384, 128, 128, O_PW + 16384},
        {d_in[I[14]], 0,     128, 512, O_F1W},
        {d_in[I[14]], 65536, 128, 512, O_F1W + 65536},
        {d_in[I[16]], 0,     512, 128, O_F2W},
        {d_in[I[16]], 65536, 512, 128, O_F2W + 65536},
        {d_in[I[22]], 0,     128, 128, O_LFW},
        {d_in[I[24]], 0,     128, 128, O_GFW},
        {d_in[I[26]], 0,     128, 128, O_FFW},
        {d_in[I[4]],  0,  128, 0, O_REDB},
        {d_in[I[8]],  0,  768, 0, O_QKVB},
        {d_in[I[11]], 0,  256, 0, O_PB},
        {d_in[I[15]], 0, 1024, 0, O_F1B},
        {d_in[I[17]], 0,  256, 0, O_F2B},
        {d_in[I[23]], 0,  128, 0, O_LFB},
        {d_in[I[25]], 0,  128, 0, O_GFB},
        {d_in[I[27]], 0,  128, 0, O_FFB},
        {d_in[I[9]],  0, 1800, 0, O_RP},
        {d_in[I[5]],  0,  256, 0, O_N1G},
        {d_in[I[6]],  0,  256, 0, O_N1B},
        {d_in[I[12]], 0,  256, 0, O_N2G},
        {d_in[I[13]], 0,  256, 0, O_N2B},
        {d_in[I[18]], 0, 1152, 0, O_OW},
        {d_in[I[19]], 0,    3, 0, O_OB},
        {d_in[I[20]], 0, 1152, 0, O_MW},
        {d_in[I[21]], 0,    3, 0, O_MB},
    };
    int cum = 0;
    for (int i = 0; i < 29; ++i) {
        p.d[i] = descs[i];
        p.start[i] = cum;
        cum += (descs[i].N > 0) ? descs[i].K * descs[i].N : descs[i].K;
    }
    p.start[29] = cum;

    prep_k<<<(cum + 255) / 256, 256, 0, stream>>>(p, wtb, xt);
    xcat_k<<<1024, 256, 0, stream>>>(xt, hx, Bbf);

    // g = Xcat @ red_w + red_b (fp32)
    gemm_mfma<5><<<dim3(1, 256), 256, 0, stream>>>(Bbf, wtu + O_REDW, wtb + O_REDB,
                                                   nullptr, g, 32768, 128, 256, 0);

    for (int d = 0; d < 2; ++d) {
        int shift = d ? 4 : 0;
        qkvln_k<<<512, 256, 0, stream>>>(g, wtu, wtb, Bbf, d, shift);
        attn_k<<<512, 256, 0, stream>>>(Bbf, wtb + O_RP + d * 900, Cbf, shift);
        gemm_mfma<3><<<dim3(1, 256), 256, 0, stream>>>(Cbf, wtu + O_PW + d * 16384,
                                                       wtb + O_PB + d * 128, nullptr, g,
                                                       32768, 128, 128, shift);
        mlp_k<<<512, 256, 0, stream>>>(g, (bf16*)Abf, wtu, wtb, d);
    }

    // local branch -> Cbf (B,C,L)
    deform_k<<<512, 256, 0, stream>>>(xt, wtb, (bf16*)Cbf);
    // fused fusion chain + LSTM -> out
    fuse3_k<<<256, 256, 0, stream>>>(Cbf, Abf, wtu, wtb, cx, d_out, xt);
}